// Round 1
// 511.862 us; speedup vs baseline: 1.0487x; 1.0487x over previous
//
#include <hip/hip_runtime.h>
#include <hip/hip_bf16.h>
#include <type_traits>

#define DEVINL __device__ __forceinline__

typedef float f32x4 __attribute__((ext_vector_type(4)));
typedef __bf16 bf16x8 __attribute__((ext_vector_type(8)));

DEVINL float bf2f(short s) {
  unsigned u = ((unsigned)(unsigned short)s) << 16;
  float f; __builtin_memcpy(&f, &u, 4); return f;
}
DEVINL short f2bf(float f) {
  unsigned u; __builtin_memcpy(&u, &f, 4);
  u += 0x7fff + ((u >> 16) & 1);          // round-nearest-even
  return (short)(u >> 16);
}

DEVINL void gl_lds16(const void* g, void* l) {
  __builtin_amdgcn_global_load_lds(
      (const __attribute__((address_space(1))) void*)g,
      (__attribute__((address_space(3))) void*)l, 16, 0, 0);
}

// XCD-aware block swizzle (T1, m192): blocks are dispatched round-robin over
// the 8 XCDs by linear id.  Remap so each XCD owns a CONTIGUOUS chunk of
// work, ordered z-slice-major with the m-index fastest -> the blocks sharing
// an A/B panel are co-resident on one XCD and hit its private L2.
// Requires nwg % 8 == 0 (all our grids: 2048 / 1024 / 256).
DEVINL void swz_blk(int& bx, int& by, int& bz) {
  const int gx = gridDim.x, gy = gridDim.y;
  const int tpz = gx * gy;
  const int nwg = tpz * gridDim.z;
  int fid = bx + gx * (by + gy * bz);
  fid = (fid & 7) * (nwg >> 3) + (fid >> 3);
  bz = fid / tpz;
  const int r = fid - bz * tpz;
  by = r % gy;            // m fastest: consecutive blocks share the B n-panel
  bx = r / gy;
}

// Coalesced epilogue via 32 KB LDS remap.  EXP: store exp(v) (unnormalized
// softmax numerator) and atomicAdd per-row sums of exp into rowsum[] — the
// 1/sum normalization is applied later in reduce_sk.
template <typename OutT, bool BIAS, bool EXP>
DEVINL void epilogue_store(f32x4 (&acc)[4][4], char* smem,
                           OutT* __restrict__ C, int ldc, int m0, int n0,
                           const float* __restrict__ bias,
                           float* __restrict__ rowsum, int t) {
  const int wave = t >> 6, lane = t & 63;
  const int quad = lane >> 4, l16 = lane & 15;
  const int arow = (wave >> 1) * 64, brow = (wave & 1) * 64;
  if constexpr (std::is_same<OutT, float>::value) {
    float* tile = (float*)smem;          // 64 x 128 fp32 per round
#pragma unroll
    for (int rnd = 0; rnd < 2; ++rnd) {
      if ((arow >> 6) == rnd) {
#pragma unroll
        for (int mi = 0; mi < 4; ++mi)
#pragma unroll
          for (int ni = 0; ni < 4; ++ni) {
            const int col = brow + ni * 16 + l16;
#pragma unroll
            for (int r = 0; r < 4; ++r) {
              const int row = mi * 16 + quad * 4 + r;
              float v = acc[mi][ni][r];
              if (BIAS) v += bias[m0 + rnd * 64 + row];
              tile[row * 128 + col] = v;
            }
          }
      }
      __syncthreads();
#pragma unroll
      for (int i = 0; i < 8; ++i) {
        const int row = wave * 16 + i * 2 + (lane >> 5);
        const int cf  = (lane & 31) * 4;
        f32x4 v = *(f32x4*)&tile[row * 128 + cf];
        *(f32x4*)&C[(long)(m0 + rnd * 64 + row) * ldc + n0 + cf] = v;
      }
      __syncthreads();
    }
  } else {
    short* tile = (short*)smem;          // 128 x 128 bf16
#pragma unroll
    for (int mi = 0; mi < 4; ++mi)
#pragma unroll
      for (int r = 0; r < 4; ++r) {
        const int row = arow + mi * 16 + quad * 4 + r;
        float rs = 0.f;
#pragma unroll
        for (int ni = 0; ni < 4; ++ni) {
          const int col = brow + ni * 16 + l16;
          float v = acc[mi][ni][r];
          if (BIAS) v += bias[m0 + row];
          if (EXP) { v = __expf(v); rs += v; }
          tile[row * 128 + col] = f2bf(v);
        }
        if (EXP) {
          // 16 lanes (l16) of this quad share `row`; reduce then 1 atomic.
          rs += __shfl_xor(rs, 1); rs += __shfl_xor(rs, 2);
          rs += __shfl_xor(rs, 4); rs += __shfl_xor(rs, 8);
          if (l16 == 0) atomicAdd(&rowsum[m0 + row], rs);
        }
      }
    __syncthreads();
#pragma unroll
    for (int i = 0; i < 8; ++i) {
      const int row = wave * 32 + i * 4 + (lane >> 4);
      const int cs  = l16 * 8;
      int4 v = *(int4*)&tile[row * 128 + cs];
      *(int4*)&C[(long)(m0 + row) * ldc + n0 + cs] = v;
    }
  }
}

// C[m][n] = sum_k A[m][k]*B[n][k] (+ bias[m]).  128x128 tile, BK=32, 4 waves.
template <typename OutT, bool BIAS, bool EXP>
__global__ __launch_bounds__(256, 4)
void gemm_nt(const short* __restrict__ A, long sA, int lda,
             const short* __restrict__ B, long sB, int ldb,
             OutT* __restrict__ C, long sC, int ldc,
             const float* __restrict__ bias, float* __restrict__ rowsum, int K)
{
  int bx = blockIdx.x, by = blockIdx.y, bz = blockIdx.z;
  swz_blk(bx, by, bz);

  A += (long)bz * sA;
  B += (long)bz * sB;
  C += (long)bz * sC;
  if (EXP) rowsum += (long)bz * 512;

  __shared__ char smem[32768];           // staging 16 KB; epilogue 32 KB
  short* As = (short*)smem;
  short* Bs = (short*)(smem + 8192);

  const int t    = threadIdx.x;
  const int wave = t >> 6, lane = t & 63;
  const int quad = lane >> 4, l16 = lane & 15;
  const int m0 = by * 128, n0 = bx * 128;
  const int lrow = t >> 2;
  const int lk8  = (t & 3) * 8;
  const int arow = (wave >> 1) * 64, brow = (wave & 1) * 64;

  f32x4 acc[4][4];
#pragma unroll
  for (int i = 0; i < 4; ++i)
#pragma unroll
    for (int j = 0; j < 4; ++j) acc[i][j] = (f32x4){0.f, 0.f, 0.f, 0.f};

  for (int k0 = 0; k0 < K; k0 += 32) {
#pragma unroll
    for (int s = 0; s < 2; ++s) {
      gl_lds16(A + (long)(m0 + s * 64 + lrow) * lda + k0 + lk8,
               (char*)As + s * 4096 + wave * 1024);
      gl_lds16(B + (long)(n0 + s * 64 + lrow) * ldb + k0 + lk8,
               (char*)Bs + s * 4096 + wave * 1024);
    }
    __syncthreads();

    bf16x8 af[4], bfr[4];
#pragma unroll
    for (int i = 0; i < 4; ++i)
      af[i] = *(const bf16x8*)&As[(arow + i * 16 + l16) * 32 + quad * 8];
#pragma unroll
    for (int i = 0; i < 4; ++i)
      bfr[i] = *(const bf16x8*)&Bs[(brow + i * 16 + l16) * 32 + quad * 8];

#pragma unroll
    for (int mi = 0; mi < 4; ++mi)
#pragma unroll
      for (int ni = 0; ni < 4; ++ni)
        acc[mi][ni] = __builtin_amdgcn_mfma_f32_16x16x32_bf16(
            af[mi], bfr[ni], acc[mi][ni], 0, 0, 0);
    __syncthreads();
  }

  epilogue_store<OutT, BIAS, EXP>(acc, smem, C, ldc, m0, n0, bias, rowsum, t);
}

// split-K NT GEMM, M=N=512, K=4096 in 4 chunks of 1024, fp32 partials.
// z = b*4 + s.  A,B per-batch stride 2097152, lda=ldb=4096.
__global__ __launch_bounds__(256, 4)
void gemm_sk(const short* __restrict__ Ab, const short* __restrict__ Bb,
             float* __restrict__ Cp)
{
  int bx = blockIdx.x, by = blockIdx.y, bz = blockIdx.z;
  swz_blk(bx, by, bz);            // 16 tiles of each z-slice contiguous on 1 XCD

  const int b = bz >> 2, s = bz & 3;
  const short* A = Ab + (long)b * 2097152;
  const short* B = Bb + (long)b * 2097152;
  float* C = Cp + (long)(s * 16 + b) * 262144;

  __shared__ char smem[32768];
  short* As = (short*)smem;
  short* Bs = (short*)(smem + 8192);

  const int t    = threadIdx.x;
  const int wave = t >> 6, lane = t & 63;
  const int quad = lane >> 4, l16 = lane & 15;
  const int m0 = by * 128, n0 = bx * 128;
  const int lrow = t >> 2;
  const int lk8  = (t & 3) * 8;
  const int arow = (wave >> 1) * 64, brow = (wave & 1) * 64;
  const int kbeg = s * 1024, kend = kbeg + 1024;

  f32x4 acc[4][4];
#pragma unroll
  for (int i = 0; i < 4; ++i)
#pragma unroll
    for (int j = 0; j < 4; ++j) acc[i][j] = (f32x4){0.f, 0.f, 0.f, 0.f};

  for (int k0 = kbeg; k0 < kend; k0 += 32) {
#pragma unroll
    for (int sb = 0; sb < 2; ++sb) {
      gl_lds16(A + (long)(m0 + sb * 64 + lrow) * 4096 + k0 + lk8,
               (char*)As + sb * 4096 + wave * 1024);
      gl_lds16(B + (long)(n0 + sb * 64 + lrow) * 4096 + k0 + lk8,
               (char*)Bs + sb * 4096 + wave * 1024);
    }
    __syncthreads();

    bf16x8 af[4], bfr[4];
#pragma unroll
    for (int i = 0; i < 4; ++i)
      af[i] = *(const bf16x8*)&As[(arow + i * 16 + l16) * 32 + quad * 8];
#pragma unroll
    for (int i = 0; i < 4; ++i)
      bfr[i] = *(const bf16x8*)&Bs[(brow + i * 16 + l16) * 32 + quad * 8];

#pragma unroll
    for (int mi = 0; mi < 4; ++mi)
#pragma unroll
      for (int ni = 0; ni < 4; ++ni)
        acc[mi][ni] = __builtin_amdgcn_mfma_f32_16x16x32_bf16(
            af[mi], bfr[ni], acc[mi][ni], 0, 0, 0);
    __syncthreads();
  }

  epilogue_store<float, false, false>(acc, smem, C, 512, m0, n0, nullptr,
                                      nullptr, t);
}

// sum 4 fp32 split-K partials, normalize by 1/rowsum (softmax denom) -> bf16
__global__ void reduce_sk(const float* __restrict__ p, short* __restrict__ o,
                          const float* __restrict__ s) {
  const long i = ((long)blockIdx.x * 256 + threadIdx.x) * 4;
  const float inv = 1.f / s[i >> 9];     // i/512 = b*512 + d
  f32x4 a = *(const f32x4*)&p[i];
  f32x4 b = *(const f32x4*)&p[i + 4194304];
  f32x4 c = *(const f32x4*)&p[i + 2 * 4194304];
  f32x4 d = *(const f32x4*)&p[i + 3 * 4194304];
  short r[4];
#pragma unroll
  for (int j = 0; j < 4; ++j) r[j] = f2bf((a[j] + b[j] + c[j] + d[j]) * inv);
  *(long*)&o[i] = *(long*)r;
}

// xT[b][l][c] = bf16(x[b][c][l]);  xb[b][c][l] = bf16(x[b][c][l])
__global__ void transpose_cast(const float* __restrict__ x,
                               short* __restrict__ xT, short* __restrict__ xb)
{
  __shared__ float tile[32][33];
  x  += (long)blockIdx.z * 2097152;
  xT += (long)blockIdx.z * 2097152;
  xb += (long)blockIdx.z * 2097152;
  const int l0 = blockIdx.x * 32, c0 = blockIdx.y * 32;
  const int tx = threadIdx.x, ty = threadIdx.y;
#pragma unroll
  for (int i = 0; i < 4; ++i) {
    float v = x[(long)(c0 + ty + i * 8) * 4096 + l0 + tx];
    tile[ty + i * 8][tx] = v;
    xb[(long)(c0 + ty + i * 8) * 4096 + l0 + tx] = f2bf(v);
  }
  __syncthreads();
#pragma unroll
  for (int i = 0; i < 4; ++i)
    xT[(long)(l0 + ty + i * 8) * 512 + c0 + tx] = f2bf(tile[tx][ty + i * 8]);
}

DEVINL float to_f(float v) { return v; }
DEVINL float to_f(short v) { return bf2f(v); }

template <typename InT, typename OutT>
__global__ void transpose_k(const InT* __restrict__ src, OutT* __restrict__ dst,
                            int R, int Cc, long ss, long ds)
{
  __shared__ float tile[32][33];
  src += (long)blockIdx.z * ss;
  dst += (long)blockIdx.z * ds;
  const int c0 = blockIdx.x * 32, r0 = blockIdx.y * 32;
  const int tx = threadIdx.x, ty = threadIdx.y;
#pragma unroll
  for (int i = 0; i < 4; ++i)
    tile[ty + i * 8][tx] = to_f(src[(long)(r0 + ty + i * 8) * Cc + c0 + tx]);
  __syncthreads();
#pragma unroll
  for (int i = 0; i < 4; ++i) {
    float v = tile[tx][ty + i * 8];
    if constexpr (std::is_same<OutT, float>::value)
      dst[(long)(c0 + ty + i * 8) * R + r0 + tx] = v;
    else
      dst[(long)(c0 + ty + i * 8) * R + r0 + tx] = f2bf(v);
  }
}

// cast both weight mats to bf16; blocks 0-31 additionally zero ssum[8192]
__global__ void cast_weights(const float* __restrict__ wq, short* __restrict__ wqb,
                             const float* __restrict__ wo, short* __restrict__ wob,
                             float* __restrict__ ssum) {
  const int i = blockIdx.x * 256 + threadIdx.x;
  if (blockIdx.x < 32) ssum[i] = 0.f;
  if (i < 786432) wqb[i] = f2bf(wq[i]);
  else            wob[i - 786432] = f2bf(wo[i - 786432]);
}

extern "C" void kernel_launch(void* const* d_in, const int* in_sizes, int n_in,
                              void* d_out, int out_size, void* d_ws, size_t ws_size,
                              hipStream_t stream) {
  // B=16, C=512, L=4096
  const float* x     = (const float*)d_in[0];
  const float* w_qkv = (const float*)d_in[1];
  const float* w_out = (const float*)d_in[2];
  const float* b_out = (const float*)d_in[3];
  float* out = (float*)d_out;

  const long CL = (long)512 * 4096;   // 2,097,152 per-batch elems
  const long CC = (long)512 * 512;

  char* ws = (char*)d_ws;
  short* xT  = (short*)(ws);                 //  67,108,864 B  [b][l][c]
  short* xb  = (short*)(ws + 67108864);      //  67,108,864 B  [b][c][l]
  short* kbf = (short*)(ws + 134217728);     //  67,108,864 B  [b][d][l]  exp(k)
  float* Pp  = (float*)(ws + 201326592);     //  67,108,864 B  [s][b][d][c] fp32
  short* P   = (short*)(ws + 268435456);     //   8,388,608 B  [b][d][c]
  short* ctx = (short*)(ws + 276824064);     //   8,388,608 B  [b][d][e]
  short* M2  = (short*)(ws + 285212672);     //   8,388,608 B  [b][o][d]
  short* M3  = (short*)(ws + 293601280);     //   8,388,608 B  [b][o][c]
  short* wqb = (short*)(ws + 301989888);     //   1,572,864 B
  short* wob = (short*)(ws + 303562752);     //     524,288 B
  short* wqT = (short*)(ws + 304087040);     //     524,288 B  w_q^T [c][d]
  // ssum[b][d] (32 KB) aliases M3's region: M3 is first written AFTER
  // reduce_sk has consumed ssum (stream-ordered), so no conflict.
  float* ssum = (float*)(ws + 293601280);

  cast_weights<<<4096, 256, 0, stream>>>(w_qkv, wqb, w_out, wob, ssum);

  // wqT[c][d] = bf16(w_q[d][c])
  transpose_k<float, short><<<dim3(16, 16, 1), dim3(32, 8), 0, stream>>>(
      w_qkv, wqT, 512, 512, 0, 0);

  // xT + xb in one pass over x
  transpose_cast<<<dim3(128, 16, 16), dim3(32, 8), 0, stream>>>(x, xT, xb);

  // kbf[b][d][l] = exp(sum_c w_k[d][c] * xT[b][l][c]); ssum[b][d] = sum_l exp
  // (softmax without max-subtraction: k ~ N(0,1), max|k| ~ 5.9 -> exp <= ~365,
  //  safe in fp32/bf16; normalization applied in reduce_sk)
  gemm_nt<short, false, true><<<dim3(32, 4, 16), 256, 0, stream>>>(
      wqb + 512 * 512, 0, 512, xT, CL, 512, kbf, CL, 4096, nullptr, ssum, 512);

  // P[b][d][c] = (1/ssum[b][d]) * sum_l exp(k)[d][l] * xb[c][l]
  gemm_sk<<<dim3(4, 4, 64), 256, 0, stream>>>(kbf, xb, Pp);
  reduce_sk<<<4096, 256, 0, stream>>>(Pp, P, ssum);

  // ctx[b][d][e] = sum_c P[d][c] * w_v[e][c]   (M=N=512, K=512)
  gemm_nt<short, false, false><<<dim3(4, 4, 16), 256, 0, stream>>>(
      P, CC, 512, wqb + 2 * 512 * 512, 0, 512, ctx, CC, 512, nullptr, nullptr, 512);

  // M2[b][o][d] = sum_e wob[o][e] * ctx[d][e]  (M=N=512, K=512)
  gemm_nt<short, false, false><<<dim3(4, 4, 16), 256, 0, stream>>>(
      wob, 0, 512, ctx, CC, 512, M2, CC, 512, nullptr, nullptr, 512);

  // M3[b][o][c] = sum_d M2[o][d] * wqT[c][d]   (M=N=512, K=512)
  gemm_nt<short, false, false><<<dim3(4, 4, 16), 256, 0, stream>>>(
      M2, CC, 512, wqT, 0, 512, M3, CC, 512, nullptr, nullptr, 512);

  // out[b][o][l] = sum_c M3[o][c] * xT[b][l][c] + b_out[o]  (fp32)
  gemm_nt<float, true, false><<<dim3(32, 4, 16), 256, 0, stream>>>(
      M3, CC, 512, xT, CL, 512, out, CL, 4096, b_out, nullptr, 512);
}

// Round 2
// 501.266 us; speedup vs baseline: 1.0709x; 1.0211x over previous
//
#include <hip/hip_runtime.h>
#include <hip/hip_bf16.h>
#include <type_traits>

#define DEVINL __device__ __forceinline__

typedef float f32x4 __attribute__((ext_vector_type(4)));
typedef __bf16 bf16x8 __attribute__((ext_vector_type(8)));

DEVINL float bf2f(short s) {
  unsigned u = ((unsigned)(unsigned short)s) << 16;
  float f; __builtin_memcpy(&f, &u, 4); return f;
}
DEVINL short f2bf(float f) {
  unsigned u; __builtin_memcpy(&u, &f, 4);
  u += 0x7fff + ((u >> 16) & 1);          // round-nearest-even
  return (short)(u >> 16);
}

DEVINL void gl_lds16(const void* g, void* l) {
  __builtin_amdgcn_global_load_lds(
      (const __attribute__((address_space(1))) void*)g,
      (__attribute__((address_space(3))) void*)l, 16, 0, 0);
}

// XCD-aware block swizzle (T1, m192): blocks are dispatched round-robin over
// the 8 XCDs by linear id.  Remap so each XCD owns a CONTIGUOUS chunk of
// work, ordered z-slice-major with the m-index fastest -> the blocks sharing
// an A/B panel are co-resident on one XCD and hit its private L2.
// Requires nwg % 8 == 0 (all our grids: 2048 / 1024 / 256).
DEVINL void swz_blk(int& bx, int& by, int& bz) {
  const int gx = gridDim.x, gy = gridDim.y;
  const int tpz = gx * gy;
  const int nwg = tpz * gridDim.z;
  int fid = bx + gx * (by + gy * bz);
  fid = (fid & 7) * (nwg >> 3) + (fid >> 3);
  bz = fid / tpz;
  const int r = fid - bz * tpz;
  by = r % gy;            // m fastest: consecutive blocks share the B n-panel
  bx = r / gy;
}

// Coalesced epilogue via 32 KB LDS remap.  EXP: store exp(v) (unnormalized
// softmax numerator) and atomicAdd per-row sums of exp into rowsum[] — the
// 1/sum normalization is applied later in reduce_sk.
template <typename OutT, bool BIAS, bool EXP>
DEVINL void epilogue_store(f32x4 (&acc)[4][4], char* smem,
                           OutT* __restrict__ C, int ldc, int m0, int n0,
                           const float* __restrict__ bias,
                           float* __restrict__ rowsum, int t) {
  const int wave = t >> 6, lane = t & 63;
  const int quad = lane >> 4, l16 = lane & 15;
  const int arow = (wave >> 1) * 64, brow = (wave & 1) * 64;
  if constexpr (std::is_same<OutT, float>::value) {
    float* tile = (float*)smem;          // 64 x 128 fp32 per round
#pragma unroll
    for (int rnd = 0; rnd < 2; ++rnd) {
      if ((arow >> 6) == rnd) {
#pragma unroll
        for (int mi = 0; mi < 4; ++mi)
#pragma unroll
          for (int ni = 0; ni < 4; ++ni) {
            const int col = brow + ni * 16 + l16;
#pragma unroll
            for (int r = 0; r < 4; ++r) {
              const int row = mi * 16 + quad * 4 + r;
              float v = acc[mi][ni][r];
              if (BIAS) v += bias[m0 + rnd * 64 + row];
              tile[row * 128 + col] = v;
            }
          }
      }
      __syncthreads();
#pragma unroll
      for (int i = 0; i < 8; ++i) {
        const int row = wave * 16 + i * 2 + (lane >> 5);
        const int cf  = (lane & 31) * 4;
        f32x4 v = *(f32x4*)&tile[row * 128 + cf];
        *(f32x4*)&C[(long)(m0 + rnd * 64 + row) * ldc + n0 + cf] = v;
      }
      __syncthreads();
    }
  } else {
    short* tile = (short*)smem;          // 128 x 128 bf16
#pragma unroll
    for (int mi = 0; mi < 4; ++mi)
#pragma unroll
      for (int r = 0; r < 4; ++r) {
        const int row = arow + mi * 16 + quad * 4 + r;
        float rs = 0.f;
#pragma unroll
        for (int ni = 0; ni < 4; ++ni) {
          const int col = brow + ni * 16 + l16;
          float v = acc[mi][ni][r];
          if (BIAS) v += bias[m0 + row];
          if (EXP) { v = __expf(v); rs += v; }
          tile[row * 128 + col] = f2bf(v);
        }
        if (EXP) {
          // 16 lanes (l16) of this quad share `row`; reduce then 1 atomic.
          rs += __shfl_xor(rs, 1); rs += __shfl_xor(rs, 2);
          rs += __shfl_xor(rs, 4); rs += __shfl_xor(rs, 8);
          if (l16 == 0) atomicAdd(&rowsum[m0 + row], rs);
        }
      }
    __syncthreads();
#pragma unroll
    for (int i = 0; i < 8; ++i) {
      const int row = wave * 32 + i * 4 + (lane >> 4);
      const int cs  = l16 * 8;
      int4 v = *(int4*)&tile[row * 128 + cs];
      *(int4*)&C[(long)(m0 + row) * ldc + n0 + cs] = v;
    }
  }
}

// C[m][n] = sum_k A[m][k]*B[n][k] (+ bias[m]).  128x128 tile, BK=32, 4 waves.
template <typename OutT, bool BIAS, bool EXP>
__global__ __launch_bounds__(256, 4)
void gemm_nt(const short* __restrict__ A, long sA, int lda,
             const short* __restrict__ B, long sB, int ldb,
             OutT* __restrict__ C, long sC, int ldc,
             const float* __restrict__ bias, float* __restrict__ rowsum, int K)
{
  int bx = blockIdx.x, by = blockIdx.y, bz = blockIdx.z;
  swz_blk(bx, by, bz);

  A += (long)bz * sA;
  B += (long)bz * sB;
  C += (long)bz * sC;
  if (EXP) rowsum += (long)bz * 512;

  __shared__ char smem[32768];           // staging 16 KB; epilogue 32 KB
  short* As = (short*)smem;
  short* Bs = (short*)(smem + 8192);

  const int t    = threadIdx.x;
  const int wave = t >> 6, lane = t & 63;
  const int quad = lane >> 4, l16 = lane & 15;
  const int m0 = by * 128, n0 = bx * 128;
  const int lrow = t >> 2;
  const int lk8  = (t & 3) * 8;
  const int arow = (wave >> 1) * 64, brow = (wave & 1) * 64;

  f32x4 acc[4][4];
#pragma unroll
  for (int i = 0; i < 4; ++i)
#pragma unroll
    for (int j = 0; j < 4; ++j) acc[i][j] = (f32x4){0.f, 0.f, 0.f, 0.f};

  for (int k0 = 0; k0 < K; k0 += 32) {
#pragma unroll
    for (int s = 0; s < 2; ++s) {
      gl_lds16(A + (long)(m0 + s * 64 + lrow) * lda + k0 + lk8,
               (char*)As + s * 4096 + wave * 1024);
      gl_lds16(B + (long)(n0 + s * 64 + lrow) * ldb + k0 + lk8,
               (char*)Bs + s * 4096 + wave * 1024);
    }
    __syncthreads();

    bf16x8 af[4], bfr[4];
#pragma unroll
    for (int i = 0; i < 4; ++i)
      af[i] = *(const bf16x8*)&As[(arow + i * 16 + l16) * 32 + quad * 8];
#pragma unroll
    for (int i = 0; i < 4; ++i)
      bfr[i] = *(const bf16x8*)&Bs[(brow + i * 16 + l16) * 32 + quad * 8];

#pragma unroll
    for (int mi = 0; mi < 4; ++mi)
#pragma unroll
      for (int ni = 0; ni < 4; ++ni)
        acc[mi][ni] = __builtin_amdgcn_mfma_f32_16x16x32_bf16(
            af[mi], bfr[ni], acc[mi][ni], 0, 0, 0);
    __syncthreads();
  }

  epilogue_store<OutT, BIAS, EXP>(acc, smem, C, ldc, m0, n0, bias, rowsum, t);
}

// split-K NT GEMM, M=N=512, K=4096 in 4 chunks of 1024, fp32 partials.
// z = b*4 + s.  A,B per-batch stride 2097152, lda=ldb=4096.
__global__ __launch_bounds__(256, 4)
void gemm_sk(const short* __restrict__ Ab, const short* __restrict__ Bb,
             float* __restrict__ Cp)
{
  int bx = blockIdx.x, by = blockIdx.y, bz = blockIdx.z;
  swz_blk(bx, by, bz);            // 16 tiles of each z-slice contiguous on 1 XCD

  const int b = bz >> 2, s = bz & 3;
  const short* A = Ab + (long)b * 2097152;
  const short* B = Bb + (long)b * 2097152;
  float* C = Cp + (long)(s * 16 + b) * 262144;

  __shared__ char smem[32768];
  short* As = (short*)smem;
  short* Bs = (short*)(smem + 8192);

  const int t    = threadIdx.x;
  const int wave = t >> 6, lane = t & 63;
  const int quad = lane >> 4, l16 = lane & 15;
  const int m0 = by * 128, n0 = bx * 128;
  const int lrow = t >> 2;
  const int lk8  = (t & 3) * 8;
  const int arow = (wave >> 1) * 64, brow = (wave & 1) * 64;
  const int kbeg = s * 1024, kend = kbeg + 1024;

  f32x4 acc[4][4];
#pragma unroll
  for (int i = 0; i < 4; ++i)
#pragma unroll
    for (int j = 0; j < 4; ++j) acc[i][j] = (f32x4){0.f, 0.f, 0.f, 0.f};

  for (int k0 = kbeg; k0 < kend; k0 += 32) {
#pragma unroll
    for (int sb = 0; sb < 2; ++sb) {
      gl_lds16(A + (long)(m0 + sb * 64 + lrow) * 4096 + k0 + lk8,
               (char*)As + sb * 4096 + wave * 1024);
      gl_lds16(B + (long)(n0 + sb * 64 + lrow) * 4096 + k0 + lk8,
               (char*)Bs + sb * 4096 + wave * 1024);
    }
    __syncthreads();

    bf16x8 af[4], bfr[4];
#pragma unroll
    for (int i = 0; i < 4; ++i)
      af[i] = *(const bf16x8*)&As[(arow + i * 16 + l16) * 32 + quad * 8];
#pragma unroll
    for (int i = 0; i < 4; ++i)
      bfr[i] = *(const bf16x8*)&Bs[(brow + i * 16 + l16) * 32 + quad * 8];

#pragma unroll
    for (int mi = 0; mi < 4; ++mi)
#pragma unroll
      for (int ni = 0; ni < 4; ++ni)
        acc[mi][ni] = __builtin_amdgcn_mfma_f32_16x16x32_bf16(
            af[mi], bfr[ni], acc[mi][ni], 0, 0, 0);
    __syncthreads();
  }

  epilogue_store<float, false, false>(acc, smem, C, 512, m0, n0, nullptr,
                                      nullptr, t);
}

// sum 4 fp32 split-K partials, normalize by 1/rowsum (softmax denom) -> bf16
__global__ void reduce_sk(const float* __restrict__ p, short* __restrict__ o,
                          const float* __restrict__ s) {
  const long i = ((long)blockIdx.x * 256 + threadIdx.x) * 4;
  const float inv = 1.f / s[i >> 9];     // i/512 = b*512 + d
  f32x4 a = *(const f32x4*)&p[i];
  f32x4 b = *(const f32x4*)&p[i + 4194304];
  f32x4 c = *(const f32x4*)&p[i + 2 * 4194304];
  f32x4 d = *(const f32x4*)&p[i + 3 * 4194304];
  short r[4];
#pragma unroll
  for (int j = 0; j < 4; ++j) r[j] = f2bf((a[j] + b[j] + c[j] + d[j]) * inv);
  *(long*)&o[i] = *(long*)r;
}

// xT[b][l][c] = bf16(x[b][c][l]);  xb[b][c][l] = bf16(x[b][c][l])
// 64x64 tile, 256 threads.  float4 loads, 8B packed-bf16 stores for BOTH
// outputs (R1: scalar 2B stores left this at 2.3 TB/s / 88us).  LDS ld=73
// shorts: column reads hit banks (18k+c') mod 32 -> <=2-way (free, m136).
__global__ void transpose_cast(const float* __restrict__ x,
                               short* __restrict__ xT, short* __restrict__ xb)
{
  __shared__ short tile[64][73];
  x  += (long)blockIdx.z * 2097152;
  xT += (long)blockIdx.z * 2097152;
  xb += (long)blockIdx.z * 2097152;
  const int l0 = blockIdx.x * 64, c0 = blockIdx.y * 64;
  const int t  = threadIdx.x;
  const int rr = t >> 4;            // 0..15
  const int q4 = (t & 15) * 4;      // 0..60
#pragma unroll
  for (int i = 0; i < 4; ++i) {
    const int r = rr + i * 16;      // c-row within tile
    f32x4 v = *(const f32x4*)&x[(long)(c0 + r) * 4096 + l0 + q4];
    short s4[4];
#pragma unroll
    for (int j = 0; j < 4; ++j) s4[j] = f2bf(v[j]);
    *(long*)&xb[(long)(c0 + r) * 4096 + l0 + q4] = *(long*)s4;
#pragma unroll
    for (int j = 0; j < 4; ++j) tile[r][q4 + j] = s4[j];
  }
  __syncthreads();
#pragma unroll
  for (int i = 0; i < 4; ++i) {
    const int l = rr + i * 16;      // l-row within tile
    short o4[4];
#pragma unroll
    for (int j = 0; j < 4; ++j) o4[j] = tile[q4 + j][l];
    *(long*)&xT[(long)(l0 + l) * 512 + c0 + q4] = *(long*)o4;
  }
}

DEVINL float to_f(float v) { return v; }
DEVINL float to_f(short v) { return bf2f(v); }

template <typename InT, typename OutT>
__global__ void transpose_k(const InT* __restrict__ src, OutT* __restrict__ dst,
                            int R, int Cc, long ss, long ds)
{
  __shared__ float tile[32][33];
  src += (long)blockIdx.z * ss;
  dst += (long)blockIdx.z * ds;
  const int c0 = blockIdx.x * 32, r0 = blockIdx.y * 32;
  const int tx = threadIdx.x, ty = threadIdx.y;
#pragma unroll
  for (int i = 0; i < 4; ++i)
    tile[ty + i * 8][tx] = to_f(src[(long)(r0 + ty + i * 8) * Cc + c0 + tx]);
  __syncthreads();
#pragma unroll
  for (int i = 0; i < 4; ++i) {
    float v = tile[tx][ty + i * 8];
    if constexpr (std::is_same<OutT, float>::value)
      dst[(long)(c0 + ty + i * 8) * R + r0 + tx] = v;
    else
      dst[(long)(c0 + ty + i * 8) * R + r0 + tx] = f2bf(v);
  }
}

// cast both weight mats to bf16; blocks 0-31 additionally zero ssum[8192]
__global__ void cast_weights(const float* __restrict__ wq, short* __restrict__ wqb,
                             const float* __restrict__ wo, short* __restrict__ wob,
                             float* __restrict__ ssum) {
  const int i = blockIdx.x * 256 + threadIdx.x;
  if (blockIdx.x < 32) ssum[i] = 0.f;
  if (i < 786432) wqb[i] = f2bf(wq[i]);
  else            wob[i - 786432] = f2bf(wo[i - 786432]);
}

extern "C" void kernel_launch(void* const* d_in, const int* in_sizes, int n_in,
                              void* d_out, int out_size, void* d_ws, size_t ws_size,
                              hipStream_t stream) {
  // B=16, C=512, L=4096
  const float* x     = (const float*)d_in[0];
  const float* w_qkv = (const float*)d_in[1];
  const float* w_out = (const float*)d_in[2];
  const float* b_out = (const float*)d_in[3];
  float* out = (float*)d_out;

  const long CL = (long)512 * 4096;   // 2,097,152 per-batch elems
  const long CC = (long)512 * 512;

  char* ws = (char*)d_ws;
  short* xT  = (short*)(ws);                 //  67,108,864 B  [b][l][c]
  short* xb  = (short*)(ws + 67108864);      //  67,108,864 B  [b][c][l]
  short* kbf = (short*)(ws + 134217728);     //  67,108,864 B  [b][d][l]  exp(k)
  float* Pp  = (float*)(ws + 201326592);     //  67,108,864 B  [s][b][d][c] fp32
  short* P   = (short*)(ws + 268435456);     //   8,388,608 B  [b][d][c]
  short* ctx = (short*)(ws + 276824064);     //   8,388,608 B  [b][d][e]
  short* M2  = (short*)(ws + 285212672);     //   8,388,608 B  [b][o][d]
  short* M3  = (short*)(ws + 293601280);     //   8,388,608 B  [b][o][c]
  short* wqb = (short*)(ws + 301989888);     //   1,572,864 B
  short* wob = (short*)(ws + 303562752);     //     524,288 B
  short* wqT = (short*)(ws + 304087040);     //     524,288 B  w_q^T [c][d]
  // ssum[b][d] (32 KB) aliases M3's region: M3 is first written AFTER
  // reduce_sk has consumed ssum (stream-ordered), so no conflict.
  float* ssum = (float*)(ws + 293601280);

  cast_weights<<<4096, 256, 0, stream>>>(w_qkv, wqb, w_out, wob, ssum);

  // wqT[c][d] = bf16(w_q[d][c])
  transpose_k<float, short><<<dim3(16, 16, 1), dim3(32, 8), 0, stream>>>(
      w_qkv, wqT, 512, 512, 0, 0);

  // xT + xb in one pass over x
  transpose_cast<<<dim3(64, 8, 16), 256, 0, stream>>>(x, xT, xb);

  // kbf[b][d][l] = exp(sum_c w_k[d][c] * xT[b][l][c]); ssum[b][d] = sum_l exp
  // (softmax without max-subtraction: k ~ N(0,1), max|k| ~ 5.9 -> exp <= ~365,
  //  safe in fp32/bf16; normalization applied in reduce_sk)
  gemm_nt<short, false, true><<<dim3(32, 4, 16), 256, 0, stream>>>(
      wqb + 512 * 512, 0, 512, xT, CL, 512, kbf, CL, 4096, nullptr, ssum, 512);

  // P[b][d][c] = (1/ssum[b][d]) * sum_l exp(k)[d][l] * xb[c][l]
  gemm_sk<<<dim3(4, 4, 64), 256, 0, stream>>>(kbf, xb, Pp);
  reduce_sk<<<4096, 256, 0, stream>>>(Pp, P, ssum);

  // ctx[b][d][e] = sum_c P[d][c] * w_v[e][c]   (M=N=512, K=512)
  gemm_nt<short, false, false><<<dim3(4, 4, 16), 256, 0, stream>>>(
      P, CC, 512, wqb + 2 * 512 * 512, 0, 512, ctx, CC, 512, nullptr, nullptr, 512);

  // M2[b][o][d] = sum_e wob[o][e] * ctx[d][e]  (M=N=512, K=512)
  gemm_nt<short, false, false><<<dim3(4, 4, 16), 256, 0, stream>>>(
      wob, 0, 512, ctx, CC, 512, M2, CC, 512, nullptr, nullptr, 512);

  // M3[b][o][c] = sum_d M2[o][d] * wqT[c][d]   (M=N=512, K=512)
  gemm_nt<short, false, false><<<dim3(4, 4, 16), 256, 0, stream>>>(
      M2, CC, 512, wqT, 0, 512, M3, CC, 512, nullptr, nullptr, 512);

  // out[b][o][l] = sum_c M3[o][c] * xT[b][l][c] + b_out[o]  (fp32)
  gemm_nt<float, true, false><<<dim3(32, 4, 16), 256, 0, stream>>>(
      M3, CC, 512, xT, CL, 512, out, CL, 4096, b_out, nullptr, 512);
}

// Round 3
// 493.806 us; speedup vs baseline: 1.0871x; 1.0151x over previous
//
#include <hip/hip_runtime.h>
#include <hip/hip_bf16.h>
#include <type_traits>

#define DEVINL __device__ __forceinline__

typedef float f32x4 __attribute__((ext_vector_type(4)));
typedef __bf16 bf16x8 __attribute__((ext_vector_type(8)));

DEVINL float bf2f(short s) {
  unsigned u = ((unsigned)(unsigned short)s) << 16;
  float f; __builtin_memcpy(&f, &u, 4); return f;
}
DEVINL short f2bf(float f) {
  unsigned u; __builtin_memcpy(&u, &f, 4);
  u += 0x7fff + ((u >> 16) & 1);          // round-nearest-even
  return (short)(u >> 16);
}

DEVINL void gl_lds16(const void* g, void* l) {
  __builtin_amdgcn_global_load_lds(
      (const __attribute__((address_space(1))) void*)g,
      (__attribute__((address_space(3))) void*)l, 16, 0, 0);
}

// XCD-aware block swizzle (T1, m192): blocks are dispatched round-robin over
// the 8 XCDs by linear id.  Remap so each XCD owns a CONTIGUOUS chunk of
// work, ordered z-slice-major with the m-index fastest -> the blocks sharing
// an A/B panel are co-resident on one XCD and hit its private L2.
// R2: gemm_sk FETCH 276 MB -> 68 MB.  Requires nwg % 8 == 0.
DEVINL void swz_blk(int& bx, int& by, int& bz) {
  const int gx = gridDim.x, gy = gridDim.y;
  const int tpz = gx * gy;
  const int nwg = tpz * gridDim.z;
  int fid = bx + gx * (by + gy * bz);
  fid = (fid & 7) * (nwg >> 3) + (fid >> 3);
  bz = fid / tpz;
  const int r = fid - bz * tpz;
  by = r % gy;            // m fastest: consecutive blocks share the B n-panel
  bx = r / gy;
}

// Coalesced epilogue via 32 KB LDS remap.  EXP: store exp(v) (unnormalized
// softmax numerator) and atomicAdd per-row sums of exp into rowsum[] — the
// 1/sum normalization is applied later in reduce_sk.
template <typename OutT, bool BIAS, bool EXP>
DEVINL void epilogue_store(f32x4 (&acc)[4][4], char* smem,
                           OutT* __restrict__ C, int ldc, int m0, int n0,
                           const float* __restrict__ bias,
                           float* __restrict__ rowsum, int t) {
  const int wave = t >> 6, lane = t & 63;
  const int quad = lane >> 4, l16 = lane & 15;
  const int arow = (wave >> 1) * 64, brow = (wave & 1) * 64;
  if constexpr (std::is_same<OutT, float>::value) {
    float* tile = (float*)smem;          // 64 x 128 fp32 per round
#pragma unroll
    for (int rnd = 0; rnd < 2; ++rnd) {
      if ((arow >> 6) == rnd) {
#pragma unroll
        for (int mi = 0; mi < 4; ++mi)
#pragma unroll
          for (int ni = 0; ni < 4; ++ni) {
            const int col = brow + ni * 16 + l16;
#pragma unroll
            for (int r = 0; r < 4; ++r) {
              const int row = mi * 16 + quad * 4 + r;
              float v = acc[mi][ni][r];
              if (BIAS) v += bias[m0 + rnd * 64 + row];
              tile[row * 128 + col] = v;
            }
          }
      }
      __syncthreads();
#pragma unroll
      for (int i = 0; i < 8; ++i) {
        const int row = wave * 16 + i * 2 + (lane >> 5);
        const int cf  = (lane & 31) * 4;
        f32x4 v = *(f32x4*)&tile[row * 128 + cf];
        *(f32x4*)&C[(long)(m0 + rnd * 64 + row) * ldc + n0 + cf] = v;
      }
      __syncthreads();
    }
  } else {
    short* tile = (short*)smem;          // 128 x 128 bf16
#pragma unroll
    for (int mi = 0; mi < 4; ++mi)
#pragma unroll
      for (int r = 0; r < 4; ++r) {
        const int row = arow + mi * 16 + quad * 4 + r;
        float rs = 0.f;
#pragma unroll
        for (int ni = 0; ni < 4; ++ni) {
          const int col = brow + ni * 16 + l16;
          float v = acc[mi][ni][r];
          if (BIAS) v += bias[m0 + row];
          if (EXP) { v = __expf(v); rs += v; }
          tile[row * 128 + col] = f2bf(v);
        }
        if (EXP) {
          // 16 lanes (l16) of this quad share `row`; reduce then 1 atomic.
          rs += __shfl_xor(rs, 1); rs += __shfl_xor(rs, 2);
          rs += __shfl_xor(rs, 4); rs += __shfl_xor(rs, 8);
          if (l16 == 0) atomicAdd(&rowsum[m0 + row], rs);
        }
      }
    __syncthreads();
#pragma unroll
    for (int i = 0; i < 8; ++i) {
      const int row = wave * 32 + i * 4 + (lane >> 4);
      const int cs  = l16 * 8;
      int4 v = *(int4*)&tile[row * 128 + cs];
      *(int4*)&C[(long)(m0 + row) * ldc + n0 + cs] = v;
    }
  }
}

// Double-buffered K-loop body (T3 minimum-2-phase, m228d: 622 TF vs 406 at
// drain-0).  Stage tile t+1 into buf^1 BEFORE computing tile t; the single
// __syncthreads at the end drains vmcnt AFTER ~300cy of ds_read+MFMA has
// covered the global-load latency.  Buffer c: A at c*16384, B at +8192.
#define GEMM_K_LOOP(A_, lda_, B_, ldb_, kbeg_, kend_)                        \
  {                                                                          \
    const int lrow = t >> 2;                                                 \
    const int lk8  = (t & 3) * 8;                                            \
    auto stage = [&](int buf, int k0) {                                      \
      _Pragma("unroll")                                                      \
      for (int s = 0; s < 2; ++s) {                                          \
        gl_lds16(A_ + (long)(m0 + s * 64 + lrow) * lda_ + k0 + lk8,          \
                 smem + buf * 16384 + s * 4096 + wave * 1024);               \
        gl_lds16(B_ + (long)(n0 + s * 64 + lrow) * ldb_ + k0 + lk8,          \
                 smem + buf * 16384 + 8192 + s * 4096 + wave * 1024);        \
      }                                                                      \
    };                                                                       \
    stage(0, kbeg_);                                                         \
    __syncthreads();                    /* buf0 staged (vmcnt drained) */    \
    int cur = 0;                                                             \
    for (int k0 = kbeg_; k0 < kend_; k0 += 32) {                             \
      if (k0 + 32 < kend_) stage(cur ^ 1, k0 + 32);  /* prefetch t+1 */      \
      const short* As = (const short*)(smem + cur * 16384);                  \
      const short* Bs = (const short*)(smem + cur * 16384 + 8192);           \
      bf16x8 af[4], bfr[4];                                                  \
      _Pragma("unroll")                                                      \
      for (int i = 0; i < 4; ++i)                                            \
        af[i] = *(const bf16x8*)&As[(arow + i * 16 + l16) * 32 + quad * 8];  \
      _Pragma("unroll")                                                      \
      for (int i = 0; i < 4; ++i)                                            \
        bfr[i] = *(const bf16x8*)&Bs[(brow + i * 16 + l16) * 32 + quad * 8]; \
      _Pragma("unroll")                                                      \
      for (int mi = 0; mi < 4; ++mi)                                         \
        _Pragma("unroll")                                                    \
        for (int ni = 0; ni < 4; ++ni)                                       \
          acc[mi][ni] = __builtin_amdgcn_mfma_f32_16x16x32_bf16(             \
              af[mi], bfr[ni], acc[mi][ni], 0, 0, 0);                        \
      __syncthreads();                  /* drains vmcnt: buf^1 now ready */  \
      cur ^= 1;                                                              \
    }                                                                        \
  }

// C[m][n] = sum_k A[m][k]*B[n][k] (+ bias[m]).  128x128 tile, BK=32, 4 waves.
template <typename OutT, bool BIAS, bool EXP>
__global__ __launch_bounds__(256, 4)
void gemm_nt(const short* __restrict__ A, long sA, int lda,
             const short* __restrict__ B, long sB, int ldb,
             OutT* __restrict__ C, long sC, int ldc,
             const float* __restrict__ bias, float* __restrict__ rowsum, int K)
{
  int bx = blockIdx.x, by = blockIdx.y, bz = blockIdx.z;
  swz_blk(bx, by, bz);

  A += (long)bz * sA;
  B += (long)bz * sB;
  C += (long)bz * sC;
  if (EXP) rowsum += (long)bz * 512;

  __shared__ char smem[32768];           // 2x16KB staging dbuf; epilogue 32KB

  const int t    = threadIdx.x;
  const int wave = t >> 6, lane = t & 63;
  const int quad = lane >> 4, l16 = lane & 15;
  const int m0 = by * 128, n0 = bx * 128;
  const int arow = (wave >> 1) * 64, brow = (wave & 1) * 64;

  f32x4 acc[4][4];
#pragma unroll
  for (int i = 0; i < 4; ++i)
#pragma unroll
    for (int j = 0; j < 4; ++j) acc[i][j] = (f32x4){0.f, 0.f, 0.f, 0.f};

  GEMM_K_LOOP(A, lda, B, ldb, 0, K)

  epilogue_store<OutT, BIAS, EXP>(acc, smem, C, ldc, m0, n0, bias, rowsum, t);
}

// split-K NT GEMM, M=N=512, K=4096 in 4 chunks of 1024, fp32 partials.
// z = b*4 + s.  A,B per-batch stride 2097152, lda=ldb=4096.
__global__ __launch_bounds__(256, 4)
void gemm_sk(const short* __restrict__ Ab, const short* __restrict__ Bb,
             float* __restrict__ Cp)
{
  int bx = blockIdx.x, by = blockIdx.y, bz = blockIdx.z;
  swz_blk(bx, by, bz);            // 16 tiles of each z-slice contiguous on 1 XCD

  const int b = bz >> 2, s = bz & 3;
  const short* A = Ab + (long)b * 2097152;
  const short* B = Bb + (long)b * 2097152;
  float* C = Cp + (long)(s * 16 + b) * 262144;

  __shared__ char smem[32768];

  const int t    = threadIdx.x;
  const int wave = t >> 6, lane = t & 63;
  const int quad = lane >> 4, l16 = lane & 15;
  const int m0 = by * 128, n0 = bx * 128;
  const int arow = (wave >> 1) * 64, brow = (wave & 1) * 64;
  const int kbeg = s * 1024, kend = kbeg + 1024;

  f32x4 acc[4][4];
#pragma unroll
  for (int i = 0; i < 4; ++i)
#pragma unroll
    for (int j = 0; j < 4; ++j) acc[i][j] = (f32x4){0.f, 0.f, 0.f, 0.f};

  GEMM_K_LOOP(A, 4096, B, 4096, kbeg, kend)

  epilogue_store<float, false, false>(acc, smem, C, 512, m0, n0, nullptr,
                                      nullptr, t);
}

// sum 4 fp32 split-K partials, normalize by 1/rowsum (softmax denom) -> bf16
__global__ void reduce_sk(const float* __restrict__ p, short* __restrict__ o,
                          const float* __restrict__ s) {
  const long i = ((long)blockIdx.x * 256 + threadIdx.x) * 4;
  const float inv = 1.f / s[i >> 9];     // i/512 = b*512 + d
  f32x4 a = *(const f32x4*)&p[i];
  f32x4 b = *(const f32x4*)&p[i + 4194304];
  f32x4 c = *(const f32x4*)&p[i + 2 * 4194304];
  f32x4 d = *(const f32x4*)&p[i + 3 * 4194304];
  short r[4];
#pragma unroll
  for (int j = 0; j < 4; ++j) r[j] = f2bf((a[j] + b[j] + c[j] + d[j]) * inv);
  *(long*)&o[i] = *(long*)r;
}

// xT[b][l][c] = bf16(x[b][c][l]);  xb[b][c][l] = bf16(x[b][c][l])
// 64x64 tile, 256 threads.  float4 loads, 8B packed-bf16 stores for BOTH
// outputs (R1: scalar 2B stores left this at 2.3 TB/s / 88us).  LDS ld=73
// shorts: column reads hit banks (18k+c') mod 32 -> <=2-way (free, m136).
__global__ void transpose_cast(const float* __restrict__ x,
                               short* __restrict__ xT, short* __restrict__ xb)
{
  __shared__ short tile[64][73];
  x  += (long)blockIdx.z * 2097152;
  xT += (long)blockIdx.z * 2097152;
  xb += (long)blockIdx.z * 2097152;
  const int l0 = blockIdx.x * 64, c0 = blockIdx.y * 64;
  const int t  = threadIdx.x;
  const int rr = t >> 4;            // 0..15
  const int q4 = (t & 15) * 4;      // 0..60
#pragma unroll
  for (int i = 0; i < 4; ++i) {
    const int r = rr + i * 16;      // c-row within tile
    f32x4 v = *(const f32x4*)&x[(long)(c0 + r) * 4096 + l0 + q4];
    short s4[4];
#pragma unroll
    for (int j = 0; j < 4; ++j) s4[j] = f2bf(v[j]);
    *(long*)&xb[(long)(c0 + r) * 4096 + l0 + q4] = *(long*)s4;
#pragma unroll
    for (int j = 0; j < 4; ++j) tile[r][q4 + j] = s4[j];
  }
  __syncthreads();
#pragma unroll
  for (int i = 0; i < 4; ++i) {
    const int l = rr + i * 16;      // l-row within tile
    short o4[4];
#pragma unroll
    for (int j = 0; j < 4; ++j) o4[j] = tile[q4 + j][l];
    *(long*)&xT[(long)(l0 + l) * 512 + c0 + q4] = *(long*)o4;
  }
}

DEVINL float to_f(float v) { return v; }
DEVINL float to_f(short v) { return bf2f(v); }

template <typename InT, typename OutT>
__global__ void transpose_k(const InT* __restrict__ src, OutT* __restrict__ dst,
                            int R, int Cc, long ss, long ds)
{
  __shared__ float tile[32][33];
  src += (long)blockIdx.z * ss;
  dst += (long)blockIdx.z * ds;
  const int c0 = blockIdx.x * 32, r0 = blockIdx.y * 32;
  const int tx = threadIdx.x, ty = threadIdx.y;
#pragma unroll
  for (int i = 0; i < 4; ++i)
    tile[ty + i * 8][tx] = to_f(src[(long)(r0 + ty + i * 8) * Cc + c0 + tx]);
  __syncthreads();
#pragma unroll
  for (int i = 0; i < 4; ++i) {
    float v = tile[tx][ty + i * 8];
    if constexpr (std::is_same<OutT, float>::value)
      dst[(long)(c0 + ty + i * 8) * R + r0 + tx] = v;
    else
      dst[(long)(c0 + ty + i * 8) * R + r0 + tx] = f2bf(v);
  }
}

// cast both weight mats to bf16; blocks 0-31 additionally zero ssum[8192]
__global__ void cast_weights(const float* __restrict__ wq, short* __restrict__ wqb,
                             const float* __restrict__ wo, short* __restrict__ wob,
                             float* __restrict__ ssum) {
  const int i = blockIdx.x * 256 + threadIdx.x;
  if (blockIdx.x < 32) ssum[i] = 0.f;
  if (i < 786432) wqb[i] = f2bf(wq[i]);
  else            wob[i - 786432] = f2bf(wo[i - 786432]);
}

extern "C" void kernel_launch(void* const* d_in, const int* in_sizes, int n_in,
                              void* d_out, int out_size, void* d_ws, size_t ws_size,
                              hipStream_t stream) {
  // B=16, C=512, L=4096
  const float* x     = (const float*)d_in[0];
  const float* w_qkv = (const float*)d_in[1];
  const float* w_out = (const float*)d_in[2];
  const float* b_out = (const float*)d_in[3];
  float* out = (float*)d_out;

  const long CL = (long)512 * 4096;   // 2,097,152 per-batch elems
  const long CC = (long)512 * 512;

  char* ws = (char*)d_ws;
  short* xT  = (short*)(ws);                 //  67,108,864 B  [b][l][c]
  short* xb  = (short*)(ws + 67108864);      //  67,108,864 B  [b][c][l]
  short* kbf = (short*)(ws + 134217728);     //  67,108,864 B  [b][d][l]  exp(k)
  float* Pp  = (float*)(ws + 201326592);     //  67,108,864 B  [s][b][d][c] fp32
  short* P   = (short*)(ws + 268435456);     //   8,388,608 B  [b][d][c]
  short* ctx = (short*)(ws + 276824064);     //   8,388,608 B  [b][d][e]
  short* M2  = (short*)(ws + 285212672);     //   8,388,608 B  [b][o][d]
  short* M3  = (short*)(ws + 293601280);     //   8,388,608 B  [b][o][c]
  short* wqb = (short*)(ws + 301989888);     //   1,572,864 B
  short* wob = (short*)(ws + 303562752);     //     524,288 B
  short* wqT = (short*)(ws + 304087040);     //     524,288 B  w_q^T [c][d]
  // ssum[b][d] (32 KB) aliases M3's region: M3 is first written AFTER
  // reduce_sk has consumed ssum (stream-ordered), so no conflict.
  float* ssum = (float*)(ws + 293601280);

  cast_weights<<<4096, 256, 0, stream>>>(w_qkv, wqb, w_out, wob, ssum);

  // wqT[c][d] = bf16(w_q[d][c])
  transpose_k<float, short><<<dim3(16, 16, 1), dim3(32, 8), 0, stream>>>(
      w_qkv, wqT, 512, 512, 0, 0);

  // xT + xb in one pass over x
  transpose_cast<<<dim3(64, 8, 16), 256, 0, stream>>>(x, xT, xb);

  // kbf[b][d][l] = exp(sum_c w_k[d][c] * xT[b][l][c]); ssum[b][d] = sum_l exp
  // (softmax without max-subtraction: k ~ N(0,1), max|k| ~ 5.9 -> exp <= ~365,
  //  safe in fp32/bf16; normalization applied in reduce_sk)
  gemm_nt<short, false, true><<<dim3(32, 4, 16), 256, 0, stream>>>(
      wqb + 512 * 512, 0, 512, xT, CL, 512, kbf, CL, 4096, nullptr, ssum, 512);

  // P[b][d][c] = (1/ssum[b][d]) * sum_l exp(k)[d][l] * xb[c][l]
  gemm_sk<<<dim3(4, 4, 64), 256, 0, stream>>>(kbf, xb, Pp);
  reduce_sk<<<4096, 256, 0, stream>>>(Pp, P, ssum);

  // ctx[b][d][e] = sum_c P[d][c] * w_v[e][c]   (M=N=512, K=512)
  gemm_nt<short, false, false><<<dim3(4, 4, 16), 256, 0, stream>>>(
      P, CC, 512, wqb + 2 * 512 * 512, 0, 512, ctx, CC, 512, nullptr, nullptr, 512);

  // M2[b][o][d] = sum_e wob[o][e] * ctx[d][e]  (M=N=512, K=512)
  gemm_nt<short, false, false><<<dim3(4, 4, 16), 256, 0, stream>>>(
      wob, 0, 512, ctx, CC, 512, M2, CC, 512, nullptr, nullptr, 512);

  // M3[b][o][c] = sum_d M2[o][d] * wqT[c][d]   (M=N=512, K=512)
  gemm_nt<short, false, false><<<dim3(4, 4, 16), 256, 0, stream>>>(
      M2, CC, 512, wqT, 0, 512, M3, CC, 512, nullptr, nullptr, 512);

  // out[b][o][l] = sum_c M3[o][c] * xT[b][l][c] + b_out[o]  (fp32)
  gemm_nt<float, true, false><<<dim3(32, 4, 16), 256, 0, stream>>>(
      M3, CC, 512, xT, CL, 512, out, CL, 4096, b_out, nullptr, 512);
}

// Round 4
// 487.914 us; speedup vs baseline: 1.1002x; 1.0121x over previous
//
#include <hip/hip_runtime.h>
#include <hip/hip_bf16.h>
#include <type_traits>

#define DEVINL __device__ __forceinline__

typedef float f32x4 __attribute__((ext_vector_type(4)));
typedef __bf16 bf16x8 __attribute__((ext_vector_type(8)));

DEVINL float bf2f(short s) {
  unsigned u = ((unsigned)(unsigned short)s) << 16;
  float f; __builtin_memcpy(&f, &u, 4); return f;
}
DEVINL short f2bf(float f) {
  unsigned u; __builtin_memcpy(&u, &f, 4);
  u += 0x7fff + ((u >> 16) & 1);          // round-nearest-even
  return (short)(u >> 16);
}

DEVINL void gl_lds16(const void* g, void* l) {
  __builtin_amdgcn_global_load_lds(
      (const __attribute__((address_space(1))) void*)g,
      (__attribute__((address_space(3))) void*)l, 16, 0, 0);
}

// XCD-aware block swizzle (T1, m192).  R2: gemm_sk FETCH 276 MB -> 68 MB.
// Requires nwg % 8 == 0 (grids: 1024/512/256/16).
DEVINL void swz_blk(int& bx, int& by, int& bz) {
  const int gx = gridDim.x, gy = gridDim.y;
  const int tpz = gx * gy;
  const int nwg = tpz * gridDim.z;
  int fid = bx + gx * (by + gy * bz);
  fid = (fid & 7) * (nwg >> 3) + (fid >> 3);
  bz = fid / tpz;
  const int r = fid - bz * tpz;
  by = r % gy;            // m fastest: consecutive blocks share the B n-panel
  bx = r / gy;
}

// ---------- 128x128 tile / 256-thread path (small GEMMs) ----------

template <typename OutT, bool BIAS, bool EXP>
DEVINL void epilogue_store(f32x4 (&acc)[4][4], char* smem,
                           OutT* __restrict__ C, int ldc, int m0, int n0,
                           const float* __restrict__ bias,
                           float* __restrict__ rowsum, int t) {
  const int wave = t >> 6, lane = t & 63;
  const int quad = lane >> 4, l16 = lane & 15;
  const int arow = (wave >> 1) * 64, brow = (wave & 1) * 64;
  if constexpr (std::is_same<OutT, float>::value) {
    float* tile = (float*)smem;          // 64 x 128 fp32 per round
#pragma unroll
    for (int rnd = 0; rnd < 2; ++rnd) {
      if ((arow >> 6) == rnd) {
#pragma unroll
        for (int mi = 0; mi < 4; ++mi)
#pragma unroll
          for (int ni = 0; ni < 4; ++ni) {
            const int col = brow + ni * 16 + l16;
#pragma unroll
            for (int r = 0; r < 4; ++r) {
              const int row = mi * 16 + quad * 4 + r;
              float v = acc[mi][ni][r];
              if (BIAS) v += bias[m0 + rnd * 64 + row];
              tile[row * 128 + col] = v;
            }
          }
      }
      __syncthreads();
#pragma unroll
      for (int i = 0; i < 8; ++i) {
        const int row = wave * 16 + i * 2 + (lane >> 5);
        const int cf  = (lane & 31) * 4;
        f32x4 v = *(f32x4*)&tile[row * 128 + cf];
        *(f32x4*)&C[(long)(m0 + rnd * 64 + row) * ldc + n0 + cf] = v;
      }
      __syncthreads();
    }
  } else {
    short* tile = (short*)smem;          // 128 x 128 bf16
#pragma unroll
    for (int mi = 0; mi < 4; ++mi)
#pragma unroll
      for (int r = 0; r < 4; ++r) {
        const int row = arow + mi * 16 + quad * 4 + r;
        float rs = 0.f;
#pragma unroll
        for (int ni = 0; ni < 4; ++ni) {
          const int col = brow + ni * 16 + l16;
          float v = acc[mi][ni][r];
          if (BIAS) v += bias[m0 + row];
          if (EXP) { v = __expf(v); rs += v; }
          tile[row * 128 + col] = f2bf(v);
        }
        if (EXP) {
          rs += __shfl_xor(rs, 1); rs += __shfl_xor(rs, 2);
          rs += __shfl_xor(rs, 4); rs += __shfl_xor(rs, 8);
          if (l16 == 0) atomicAdd(&rowsum[m0 + row], rs);
        }
      }
    __syncthreads();
#pragma unroll
    for (int i = 0; i < 8; ++i) {
      const int row = wave * 32 + i * 4 + (lane >> 4);
      const int cs  = l16 * 8;
      int4 v = *(int4*)&tile[row * 128 + cs];
      *(int4*)&C[(long)(m0 + row) * ldc + n0 + cs] = v;
    }
  }
}

// 2-phase double-buffered K loop (T3 minimum form).
#define GEMM_K_LOOP(A_, lda_, B_, ldb_, kbeg_, kend_)                        \
  {                                                                          \
    const int lrow = t >> 2;                                                 \
    const int lk8  = (t & 3) * 8;                                            \
    auto stage = [&](int buf, int k0) {                                      \
      _Pragma("unroll")                                                      \
      for (int s = 0; s < 2; ++s) {                                          \
        gl_lds16(A_ + (long)(m0 + s * 64 + lrow) * lda_ + k0 + lk8,          \
                 smem + buf * 16384 + s * 4096 + wave * 1024);               \
        gl_lds16(B_ + (long)(n0 + s * 64 + lrow) * ldb_ + k0 + lk8,          \
                 smem + buf * 16384 + 8192 + s * 4096 + wave * 1024);        \
      }                                                                      \
    };                                                                       \
    stage(0, kbeg_);                                                         \
    __syncthreads();                                                         \
    int cur = 0;                                                             \
    for (int k0 = kbeg_; k0 < kend_; k0 += 32) {                             \
      if (k0 + 32 < kend_) stage(cur ^ 1, k0 + 32);                          \
      const short* As = (const short*)(smem + cur * 16384);                  \
      const short* Bs = (const short*)(smem + cur * 16384 + 8192);           \
      bf16x8 af[4], bfr[4];                                                  \
      _Pragma("unroll")                                                      \
      for (int i = 0; i < 4; ++i)                                            \
        af[i] = *(const bf16x8*)&As[(arow + i * 16 + l16) * 32 + quad * 8];  \
      _Pragma("unroll")                                                      \
      for (int i = 0; i < 4; ++i)                                            \
        bfr[i] = *(const bf16x8*)&Bs[(brow + i * 16 + l16) * 32 + quad * 8]; \
      _Pragma("unroll")                                                      \
      for (int mi = 0; mi < 4; ++mi)                                         \
        _Pragma("unroll")                                                    \
        for (int ni = 0; ni < 4; ++ni)                                       \
          acc[mi][ni] = __builtin_amdgcn_mfma_f32_16x16x32_bf16(             \
              af[mi], bfr[ni], acc[mi][ni], 0, 0, 0);                        \
      __syncthreads();                                                       \
      cur ^= 1;                                                              \
    }                                                                        \
  }

template <typename OutT, bool BIAS, bool EXP>
__global__ __launch_bounds__(256, 4)
void gemm_nt(const short* __restrict__ A, long sA, int lda,
             const short* __restrict__ B, long sB, int ldb,
             OutT* __restrict__ C, long sC, int ldc,
             const float* __restrict__ bias, float* __restrict__ rowsum, int K)
{
  int bx = blockIdx.x, by = blockIdx.y, bz = blockIdx.z;
  swz_blk(bx, by, bz);

  A += (long)bz * sA;
  B += (long)bz * sB;
  C += (long)bz * sC;
  if (EXP) rowsum += (long)bz * 512;

  __shared__ char smem[32768];

  const int t    = threadIdx.x;
  const int wave = t >> 6, lane = t & 63;
  const int quad = lane >> 4, l16 = lane & 15;
  const int m0 = by * 128, n0 = bx * 128;
  const int arow = (wave >> 1) * 64, brow = (wave & 1) * 64;

  f32x4 acc[4][4];
#pragma unroll
  for (int i = 0; i < 4; ++i)
#pragma unroll
    for (int j = 0; j < 4; ++j) acc[i][j] = (f32x4){0.f, 0.f, 0.f, 0.f};

  GEMM_K_LOOP(A, lda, B, ldb, 0, K)

  epilogue_store<OutT, BIAS, EXP>(acc, smem, C, ldc, m0, n0, bias, rowsum, t);
}

// ---------- 128x256 tile / 512-thread / 8-wave path (big GEMMs) ----------
// R4: K=512 is short (16 K-steps); 2048-block 128^2 config spent ~50% of
// block life in prologue+epilogue (MfmaUtil 16.6%).  128x256 halves block
// count, cuts staged bytes/FLOP 25% (A-tile shared by 8 waves), halves
// prologue/epilogue count.  LDS 2x24KB dbuf = 48KB -> 3 blocks/CU.

template <typename OutT, bool BIAS, bool EXP>
DEVINL void epilogue_store_wide(f32x4 (&acc)[4][4], char* smem,
                                OutT* __restrict__ C, int ldc, int m0, int n0,
                                const float* __restrict__ bias,
                                float* __restrict__ rowsum, int t) {
  const int wave = t >> 6, lane = t & 63;
  const int quad = lane >> 4, l16 = lane & 15;
  const int arow = (wave >> 2) * 64, brow = (wave & 3) * 64;
  const int rn_w = brow >> 7;          // this wave's n-round
  const int colb = brow & 64;          // col base within the 128-wide round
  if constexpr (std::is_same<OutT, float>::value) {
    float* tile = (float*)smem;        // 64 x 128 fp32 per round
    const int rm_w = arow >> 6;
#pragma unroll
    for (int rm = 0; rm < 2; ++rm)
#pragma unroll
      for (int rn = 0; rn < 2; ++rn) {
        if (rm_w == rm && rn_w == rn) {
#pragma unroll
          for (int mi = 0; mi < 4; ++mi)
#pragma unroll
            for (int ni = 0; ni < 4; ++ni)
#pragma unroll
              for (int r = 0; r < 4; ++r) {
                const int row = mi * 16 + quad * 4 + r;
                float v = acc[mi][ni][r];
                if (BIAS) v += bias[m0 + rm * 64 + row];
                tile[row * 128 + colb + ni * 16 + l16] = v;
              }
        }
        __syncthreads();
#pragma unroll
        for (int i = 0; i < 4; ++i) {
          const int row = wave * 8 + i * 2 + (lane >> 5);
          const int cf  = (lane & 31) * 4;
          *(f32x4*)&C[(long)(m0 + rm * 64 + row) * ldc + n0 + rn * 128 + cf] =
              *(f32x4*)&tile[row * 128 + cf];
        }
        __syncthreads();
      }
  } else {
    if (EXP) {                         // exp + per-row sum atomics, in-place
#pragma unroll
      for (int mi = 0; mi < 4; ++mi)
#pragma unroll
        for (int r = 0; r < 4; ++r) {
          const int row = arow + mi * 16 + quad * 4 + r;
          float rs = 0.f;
#pragma unroll
          for (int ni = 0; ni < 4; ++ni) {
            float v = __expf(acc[mi][ni][r]);
            acc[mi][ni][r] = v; rs += v;
          }
          rs += __shfl_xor(rs, 1); rs += __shfl_xor(rs, 2);
          rs += __shfl_xor(rs, 4); rs += __shfl_xor(rs, 8);
          if (l16 == 0) atomicAdd(&rowsum[m0 + row], rs);
        }
    }
    short* tile = (short*)smem;        // 128 x 128 bf16 per round
#pragma unroll
    for (int rn = 0; rn < 2; ++rn) {
      if (rn_w == rn) {
#pragma unroll
        for (int mi = 0; mi < 4; ++mi)
#pragma unroll
          for (int ni = 0; ni < 4; ++ni)
#pragma unroll
            for (int r = 0; r < 4; ++r) {
              const int row = arow + mi * 16 + quad * 4 + r;
              float v = acc[mi][ni][r];
              if (BIAS) v += bias[m0 + row];
              tile[row * 128 + colb + ni * 16 + l16] = f2bf(v);
            }
      }
      __syncthreads();
#pragma unroll
      for (int i = 0; i < 4; ++i) {
        const int row = wave * 16 + i * 4 + (lane >> 4);
        const int cs  = l16 * 8;
        *(int4*)&C[(long)(m0 + row) * ldc + n0 + rn * 128 + cs] =
            *(int4*)&tile[row * 128 + cs];
      }
      __syncthreads();
    }
  }
}

// A-tile 128x32 (8KB, 1 pass), B-tile 256x32 (16KB, 2 passes), dbuf 48KB.
#define WIDE_K_LOOP(A_, lda_, B_, ldb_, kbeg_, kend_)                        \
  {                                                                          \
    const int lrow = t >> 2;           /* 0..127 */                          \
    const int lk8  = (t & 3) * 8;                                            \
    auto stage = [&](int buf, int k0) {                                      \
      gl_lds16(A_ + (long)(m0 + lrow) * lda_ + k0 + lk8,                     \
               smem + buf * 24576 + wave * 1024);                            \
      _Pragma("unroll")                                                      \
      for (int s = 0; s < 2; ++s)                                            \
        gl_lds16(B_ + (long)(n0 + s * 128 + lrow) * ldb_ + k0 + lk8,         \
                 smem + buf * 24576 + 8192 + s * 8192 + wave * 1024);        \
    };                                                                       \
    stage(0, kbeg_);                                                         \
    __syncthreads();                                                         \
    int cur = 0;                                                             \
    for (int k0 = kbeg_; k0 < kend_; k0 += 32) {                             \
      if (k0 + 32 < kend_) stage(cur ^ 1, k0 + 32);                          \
      const short* As = (const short*)(smem + cur * 24576);                  \
      const short* Bs = (const short*)(smem + cur * 24576 + 8192);           \
      bf16x8 af[4], bfr[4];                                                  \
      _Pragma("unroll")                                                      \
      for (int i = 0; i < 4; ++i)                                            \
        af[i] = *(const bf16x8*)&As[(arow + i * 16 + l16) * 32 + quad * 8];  \
      _Pragma("unroll")                                                      \
      for (int i = 0; i < 4; ++i)                                            \
        bfr[i] = *(const bf16x8*)&Bs[(brow + i * 16 + l16) * 32 + quad * 8]; \
      _Pragma("unroll")                                                      \
      for (int mi = 0; mi < 4; ++mi)                                         \
        _Pragma("unroll")                                                    \
        for (int ni = 0; ni < 4; ++ni)                                       \
          acc[mi][ni] = __builtin_amdgcn_mfma_f32_16x16x32_bf16(             \
              af[mi], bfr[ni], acc[mi][ni], 0, 0, 0);                        \
      __syncthreads();                                                       \
      cur ^= 1;                                                              \
    }                                                                        \
  }

template <typename OutT, bool BIAS, bool EXP>
__global__ __launch_bounds__(512, 4)
void gemm_nt_wide(const short* __restrict__ A, long sA, int lda,
                  const short* __restrict__ B, long sB, int ldb,
                  OutT* __restrict__ C, long sC, int ldc,
                  const float* __restrict__ bias, float* __restrict__ rowsum,
                  int K)
{
  int bx = blockIdx.x, by = blockIdx.y, bz = blockIdx.z;
  swz_blk(bx, by, bz);

  A += (long)bz * sA;
  B += (long)bz * sB;
  C += (long)bz * sC;
  if (EXP) rowsum += (long)bz * 512;

  __shared__ char smem[49152];

  const int t    = threadIdx.x;
  const int wave = t >> 6, lane = t & 63;
  const int quad = lane >> 4, l16 = lane & 15;
  const int m0 = by * 128, n0 = bx * 256;
  const int arow = (wave >> 2) * 64, brow = (wave & 3) * 64;

  f32x4 acc[4][4];
#pragma unroll
  for (int i = 0; i < 4; ++i)
#pragma unroll
    for (int j = 0; j < 4; ++j) acc[i][j] = (f32x4){0.f, 0.f, 0.f, 0.f};

  WIDE_K_LOOP(A, lda, B, ldb, 0, K)

  epilogue_store_wide<OutT, BIAS, EXP>(acc, smem, C, ldc, m0, n0, bias,
                                       rowsum, t);
}

// split-K wide: M=512, N=512, K=4096 in 4 chunks of 1024, fp32 partials.
__global__ __launch_bounds__(512, 4)
void gemm_sk_wide(const short* __restrict__ Ab, const short* __restrict__ Bb,
                  float* __restrict__ Cp)
{
  int bx = blockIdx.x, by = blockIdx.y, bz = blockIdx.z;
  swz_blk(bx, by, bz);

  const int b = bz >> 2, s = bz & 3;
  const short* A = Ab + (long)b * 2097152;
  const short* B = Bb + (long)b * 2097152;
  float* C = Cp + (long)(s * 16 + b) * 262144;

  __shared__ char smem[49152];

  const int t    = threadIdx.x;
  const int wave = t >> 6, lane = t & 63;
  const int quad = lane >> 4, l16 = lane & 15;
  const int m0 = by * 128, n0 = bx * 256;
  const int arow = (wave >> 2) * 64, brow = (wave & 3) * 64;
  const int kbeg = s * 1024, kend = kbeg + 1024;

  f32x4 acc[4][4];
#pragma unroll
  for (int i = 0; i < 4; ++i)
#pragma unroll
    for (int j = 0; j < 4; ++j) acc[i][j] = (f32x4){0.f, 0.f, 0.f, 0.f};

  WIDE_K_LOOP(A, 4096, B, 4096, kbeg, kend)

  epilogue_store_wide<float, false, false>(acc, smem, C, 512, m0, n0, nullptr,
                                           nullptr, t);
}

// sum 4 fp32 split-K partials, normalize by 1/rowsum (softmax denom) -> bf16
__global__ void reduce_sk(const float* __restrict__ p, short* __restrict__ o,
                          const float* __restrict__ s) {
  const long i = ((long)blockIdx.x * 256 + threadIdx.x) * 4;
  const float inv = 1.f / s[i >> 9];     // i/512 = b*512 + d
  f32x4 a = *(const f32x4*)&p[i];
  f32x4 b = *(const f32x4*)&p[i + 4194304];
  f32x4 c = *(const f32x4*)&p[i + 2 * 4194304];
  f32x4 d = *(const f32x4*)&p[i + 3 * 4194304];
  short r[4];
#pragma unroll
  for (int j = 0; j < 4; ++j) r[j] = f2bf((a[j] + b[j] + c[j] + d[j]) * inv);
  *(long*)&o[i] = *(long*)r;
}

// xT[b][l][c] = bf16(x[b][c][l]);  xb[b][c][l] = bf16(x[b][c][l])
__global__ void transpose_cast(const float* __restrict__ x,
                               short* __restrict__ xT, short* __restrict__ xb)
{
  __shared__ short tile[64][73];
  x  += (long)blockIdx.z * 2097152;
  xT += (long)blockIdx.z * 2097152;
  xb += (long)blockIdx.z * 2097152;
  const int l0 = blockIdx.x * 64, c0 = blockIdx.y * 64;
  const int t  = threadIdx.x;
  const int rr = t >> 4;            // 0..15
  const int q4 = (t & 15) * 4;      // 0..60
#pragma unroll
  for (int i = 0; i < 4; ++i) {
    const int r = rr + i * 16;      // c-row within tile
    f32x4 v = *(const f32x4*)&x[(long)(c0 + r) * 4096 + l0 + q4];
    short s4[4];
#pragma unroll
    for (int j = 0; j < 4; ++j) s4[j] = f2bf(v[j]);
    *(long*)&xb[(long)(c0 + r) * 4096 + l0 + q4] = *(long*)s4;
#pragma unroll
    for (int j = 0; j < 4; ++j) tile[r][q4 + j] = s4[j];
  }
  __syncthreads();
#pragma unroll
  for (int i = 0; i < 4; ++i) {
    const int l = rr + i * 16;      // l-row within tile
    short o4[4];
#pragma unroll
    for (int j = 0; j < 4; ++j) o4[j] = tile[q4 + j][l];
    *(long*)&xT[(long)(l0 + l) * 512 + c0 + q4] = *(long*)o4;
  }
}

DEVINL float to_f(float v) { return v; }
DEVINL float to_f(short v) { return bf2f(v); }

template <typename InT, typename OutT>
__global__ void transpose_k(const InT* __restrict__ src, OutT* __restrict__ dst,
                            int R, int Cc, long ss, long ds)
{
  __shared__ float tile[32][33];
  src += (long)blockIdx.z * ss;
  dst += (long)blockIdx.z * ds;
  const int c0 = blockIdx.x * 32, r0 = blockIdx.y * 32;
  const int tx = threadIdx.x, ty = threadIdx.y;
#pragma unroll
  for (int i = 0; i < 4; ++i)
    tile[ty + i * 8][tx] = to_f(src[(long)(r0 + ty + i * 8) * Cc + c0 + tx]);
  __syncthreads();
#pragma unroll
  for (int i = 0; i < 4; ++i) {
    float v = tile[tx][ty + i * 8];
    if constexpr (std::is_same<OutT, float>::value)
      dst[(long)(c0 + ty + i * 8) * R + r0 + tx] = v;
    else
      dst[(long)(c0 + ty + i * 8) * R + r0 + tx] = f2bf(v);
  }
}

// cast both weight mats to bf16; blocks 0-31 additionally zero ssum[8192]
__global__ void cast_weights(const float* __restrict__ wq, short* __restrict__ wqb,
                             const float* __restrict__ wo, short* __restrict__ wob,
                             float* __restrict__ ssum) {
  const int i = blockIdx.x * 256 + threadIdx.x;
  if (blockIdx.x < 32) ssum[i] = 0.f;
  if (i < 786432) wqb[i] = f2bf(wq[i]);
  else            wob[i - 786432] = f2bf(wo[i - 786432]);
}

extern "C" void kernel_launch(void* const* d_in, const int* in_sizes, int n_in,
                              void* d_out, int out_size, void* d_ws, size_t ws_size,
                              hipStream_t stream) {
  // B=16, C=512, L=4096
  const float* x     = (const float*)d_in[0];
  const float* w_qkv = (const float*)d_in[1];
  const float* w_out = (const float*)d_in[2];
  const float* b_out = (const float*)d_in[3];
  float* out = (float*)d_out;

  const long CL = (long)512 * 4096;   // 2,097,152 per-batch elems
  const long CC = (long)512 * 512;

  char* ws = (char*)d_ws;
  short* xT  = (short*)(ws);                 //  67,108,864 B  [b][l][c]
  short* xb  = (short*)(ws + 67108864);      //  67,108,864 B  [b][c][l]
  short* kbf = (short*)(ws + 134217728);     //  67,108,864 B  [b][d][l]  exp(k)
  float* Pp  = (float*)(ws + 201326592);     //  67,108,864 B  [s][b][d][c] fp32
  short* P   = (short*)(ws + 268435456);     //   8,388,608 B  [b][d][c]
  short* U   = (short*)(ws + 276824064);     //     524,288 B  U = w_o·w_v [o][c]
  short* wvT = (short*)(ws + 277348352);     //     524,288 B  w_v^T [c][e]
  short* M2  = (short*)(ws + 285212672);     //   8,388,608 B  [b][o][d]
  short* M3  = (short*)(ws + 293601280);     //   8,388,608 B  [b][o][c]
  short* wqb = (short*)(ws + 301989888);     //   1,572,864 B
  short* wob = (short*)(ws + 303562752);     //     524,288 B
  short* wqT = (short*)(ws + 304087040);     //     524,288 B  w_q^T [c][d]
  // ssum[b][d] (32 KB) aliases M3's region: M3 is first written AFTER
  // reduce_sk has consumed ssum (stream-ordered), so no conflict.
  float* ssum = (float*)(ws + 293601280);

  cast_weights<<<4096, 256, 0, stream>>>(w_qkv, wqb, w_out, wob, ssum);

  // wqT[c][d] = bf16(w_q[d][c]);  wvT[c][e] = bf16(w_v[e][c])
  transpose_k<float, short><<<dim3(16, 16, 1), dim3(32, 8), 0, stream>>>(
      w_qkv, wqT, 512, 512, 0, 0);
  transpose_k<short, short><<<dim3(16, 16, 1), dim3(32, 8), 0, stream>>>(
      wqb + 2 * CC, wvT, 512, 512, 0, 0);

  // U[o][c] = sum_e w_o[o][e]·w_v[e][c]  (batch-independent fold of the
  // old per-batch ctx GEMM: M2 = w_o·ctx^T = (w_o·w_v)·P^T = U·P^T)
  gemm_nt<short, false, false><<<dim3(4, 4, 1), 256, 0, stream>>>(
      wob, 0, 512, wvT, 0, 512, U, 0, 512, nullptr, nullptr, 512);

  // xT + xb in one pass over x
  transpose_cast<<<dim3(64, 8, 16), 256, 0, stream>>>(x, xT, xb);

  // kbf[b][d][l] = exp(sum_c w_k[d][c]·xT[b][l][c]); ssum[b][d] = sum_l exp
  gemm_nt_wide<short, false, true><<<dim3(16, 4, 16), 512, 0, stream>>>(
      wqb + CC, 0, 512, xT, CL, 512, kbf, CL, 4096, nullptr, ssum, 512);

  // P[b][d][c] = (1/ssum[b][d]) * sum_l exp(k)[d][l]·xb[c][l]
  gemm_sk_wide<<<dim3(2, 4, 64), 512, 0, stream>>>(kbf, xb, Pp);
  reduce_sk<<<4096, 256, 0, stream>>>(Pp, P, ssum);

  // M2[b][o][d] = sum_c U[o][c]·P[b][d][c]   (M=N=512, K=512)
  gemm_nt<short, false, false><<<dim3(4, 4, 16), 256, 0, stream>>>(
      U, 0, 512, P, CC, 512, M2, CC, 512, nullptr, nullptr, 512);

  // M3[b][o][c] = sum_d M2[o][d]·wqT[c][d]   (M=N=512, K=512)
  gemm_nt<short, false, false><<<dim3(4, 4, 16), 256, 0, stream>>>(
      M2, CC, 512, wqT, 0, 512, M3, CC, 512, nullptr, nullptr, 512);

  // out[b][o][l] = sum_c M3[o][c]·xT[b][l][c] + b_out[o]  (fp32)
  gemm_nt_wide<float, true, false><<<dim3(16, 4, 16), 512, 0, stream>>>(
      M3, CC, 512, xT, CL, 512, out, CL, 4096, b_out, nullptr, 512);
}

// Round 5
// 482.324 us; speedup vs baseline: 1.1129x; 1.0116x over previous
//
#include <hip/hip_runtime.h>
#include <hip/hip_bf16.h>
#include <type_traits>

#define DEVINL __device__ __forceinline__

typedef float f32x4 __attribute__((ext_vector_type(4)));
typedef __bf16 bf16x8 __attribute__((ext_vector_type(8)));

DEVINL float bf2f(short s) {
  unsigned u = ((unsigned)(unsigned short)s) << 16;
  float f; __builtin_memcpy(&f, &u, 4); return f;
}
DEVINL short f2bf(float f) {
  unsigned u; __builtin_memcpy(&u, &f, 4);
  u += 0x7fff + ((u >> 16) & 1);          // round-nearest-even
  return (short)(u >> 16);
}

DEVINL void gl_lds16(const void* g, void* l) {
  __builtin_amdgcn_global_load_lds(
      (const __attribute__((address_space(1))) void*)g,
      (__attribute__((address_space(3))) void*)l, 16, 0, 0);
}

// XCD-aware block swizzle (T1, m192).  R2: gemm_sk FETCH 276 MB -> 68 MB.
// Requires nwg % 8 == 0 (grids: 1024/512/256/16).
DEVINL void swz_blk(int& bx, int& by, int& bz) {
  const int gx = gridDim.x, gy = gridDim.y;
  const int tpz = gx * gy;
  const int nwg = tpz * gridDim.z;
  int fid = bx + gx * (by + gy * bz);
  fid = (fid & 7) * (nwg >> 3) + (fid >> 3);
  bz = fid / tpz;
  const int r = fid - bz * tpz;
  by = r % gy;            // m fastest: consecutive blocks share the B n-panel
  bx = r / gy;
}

// ---------- 128x128 tile / 256-thread path (small GEMMs) ----------

template <typename OutT, bool BIAS, bool EXP>
DEVINL void epilogue_store(f32x4 (&acc)[4][4], char* smem,
                           OutT* __restrict__ C, int ldc, int m0, int n0,
                           const float* __restrict__ bias,
                           float* __restrict__ rowsum, int t) {
  const int wave = t >> 6, lane = t & 63;
  const int quad = lane >> 4, l16 = lane & 15;
  const int arow = (wave >> 1) * 64, brow = (wave & 1) * 64;
  if constexpr (std::is_same<OutT, float>::value) {
    float* tile = (float*)smem;          // 64 x 128 fp32 per round
#pragma unroll
    for (int rnd = 0; rnd < 2; ++rnd) {
      if ((arow >> 6) == rnd) {
#pragma unroll
        for (int mi = 0; mi < 4; ++mi)
#pragma unroll
          for (int ni = 0; ni < 4; ++ni) {
            const int col = brow + ni * 16 + l16;
#pragma unroll
            for (int r = 0; r < 4; ++r) {
              const int row = mi * 16 + quad * 4 + r;
              float v = acc[mi][ni][r];
              if (BIAS) v += bias[m0 + rnd * 64 + row];
              tile[row * 128 + col] = v;
            }
          }
      }
      __syncthreads();
#pragma unroll
      for (int i = 0; i < 8; ++i) {
        const int row = wave * 16 + i * 2 + (lane >> 5);
        const int cf  = (lane & 31) * 4;
        f32x4 v = *(f32x4*)&tile[row * 128 + cf];
        *(f32x4*)&C[(long)(m0 + rnd * 64 + row) * ldc + n0 + cf] = v;
      }
      __syncthreads();
    }
  } else {
    short* tile = (short*)smem;          // 128 x 128 bf16
#pragma unroll
    for (int mi = 0; mi < 4; ++mi)
#pragma unroll
      for (int r = 0; r < 4; ++r) {
        const int row = arow + mi * 16 + quad * 4 + r;
        float rs = 0.f;
#pragma unroll
        for (int ni = 0; ni < 4; ++ni) {
          const int col = brow + ni * 16 + l16;
          float v = acc[mi][ni][r];
          if (BIAS) v += bias[m0 + row];
          if (EXP) { v = __expf(v); rs += v; }
          tile[row * 128 + col] = f2bf(v);
        }
        if (EXP) {
          rs += __shfl_xor(rs, 1); rs += __shfl_xor(rs, 2);
          rs += __shfl_xor(rs, 4); rs += __shfl_xor(rs, 8);
          if (l16 == 0) atomicAdd(&rowsum[m0 + row], rs);
        }
      }
    __syncthreads();
#pragma unroll
    for (int i = 0; i < 8; ++i) {
      const int row = wave * 32 + i * 4 + (lane >> 4);
      const int cs  = l16 * 8;
      int4 v = *(int4*)&tile[row * 128 + cs];
      *(int4*)&C[(long)(m0 + row) * ldc + n0 + cs] = v;
    }
  }
}

// 2-phase double-buffered K loop (small GEMMs, unchanged).
#define GEMM_K_LOOP(A_, lda_, B_, ldb_, kbeg_, kend_)                        \
  {                                                                          \
    const int lrow = t >> 2;                                                 \
    const int lk8  = (t & 3) * 8;                                            \
    auto stage = [&](int buf, int k0) {                                      \
      _Pragma("unroll")                                                      \
      for (int s = 0; s < 2; ++s) {                                          \
        gl_lds16(A_ + (long)(m0 + s * 64 + lrow) * lda_ + k0 + lk8,          \
                 smem + buf * 16384 + s * 4096 + wave * 1024);               \
        gl_lds16(B_ + (long)(n0 + s * 64 + lrow) * ldb_ + k0 + lk8,          \
                 smem + buf * 16384 + 8192 + s * 4096 + wave * 1024);        \
      }                                                                      \
    };                                                                       \
    stage(0, kbeg_);                                                         \
    __syncthreads();                                                         \
    int cur = 0;                                                             \
    for (int k0 = kbeg_; k0 < kend_; k0 += 32) {                             \
      if (k0 + 32 < kend_) stage(cur ^ 1, k0 + 32);                          \
      const short* As = (const short*)(smem + cur * 16384);                  \
      const short* Bs = (const short*)(smem + cur * 16384 + 8192);           \
      bf16x8 af[4], bfr[4];                                                  \
      _Pragma("unroll")                                                      \
      for (int i = 0; i < 4; ++i)                                            \
        af[i] = *(const bf16x8*)&As[(arow + i * 16 + l16) * 32 + quad * 8];  \
      _Pragma("unroll")                                                      \
      for (int i = 0; i < 4; ++i)                                            \
        bfr[i] = *(const bf16x8*)&Bs[(brow + i * 16 + l16) * 32 + quad * 8]; \
      _Pragma("unroll")                                                      \
      for (int mi = 0; mi < 4; ++mi)                                         \
        _Pragma("unroll")                                                    \
        for (int ni = 0; ni < 4; ++ni)                                       \
          acc[mi][ni] = __builtin_amdgcn_mfma_f32_16x16x32_bf16(             \
              af[mi], bfr[ni], acc[mi][ni], 0, 0, 0);                        \
      __syncthreads();                                                       \
      cur ^= 1;                                                              \
    }                                                                        \
  }

template <typename OutT, bool BIAS, bool EXP>
__global__ __launch_bounds__(256, 4)
void gemm_nt(const short* __restrict__ A, long sA, int lda,
             const short* __restrict__ B, long sB, int ldb,
             OutT* __restrict__ C, long sC, int ldc,
             const float* __restrict__ bias, float* __restrict__ rowsum, int K)
{
  int bx = blockIdx.x, by = blockIdx.y, bz = blockIdx.z;
  swz_blk(bx, by, bz);

  A += (long)bz * sA;
  B += (long)bz * sB;
  C += (long)bz * sC;
  if (EXP) rowsum += (long)bz * 512;

  __shared__ char smem[32768];

  const int t    = threadIdx.x;
  const int wave = t >> 6, lane = t & 63;
  const int quad = lane >> 4, l16 = lane & 15;
  const int m0 = by * 128, n0 = bx * 128;
  const int arow = (wave >> 1) * 64, brow = (wave & 1) * 64;

  f32x4 acc[4][4];
#pragma unroll
  for (int i = 0; i < 4; ++i)
#pragma unroll
    for (int j = 0; j < 4; ++j) acc[i][j] = (f32x4){0.f, 0.f, 0.f, 0.f};

  GEMM_K_LOOP(A, lda, B, ldb, 0, K)

  epilogue_store<OutT, BIAS, EXP>(acc, smem, C, ldc, m0, n0, bias, rowsum, t);
}

// ---------- 128x256 tile / 512-thread / 8-wave path (big GEMMs) ----------

template <typename OutT, bool BIAS, bool EXP>
DEVINL void epilogue_store_wide(f32x4 (&acc)[4][4], char* smem,
                                OutT* __restrict__ C, int ldc, int m0, int n0,
                                const float* __restrict__ bias,
                                float* __restrict__ rowsum, int t) {
  const int wave = t >> 6, lane = t & 63;
  const int quad = lane >> 4, l16 = lane & 15;
  const int arow = (wave >> 2) * 64, brow = (wave & 3) * 64;
  const int rn_w = brow >> 7;          // this wave's n-round
  const int colb = brow & 64;          // col base within the 128-wide round
  if constexpr (std::is_same<OutT, float>::value) {
    float* tile = (float*)smem;        // 64 x 128 fp32 per round
    const int rm_w = arow >> 6;
#pragma unroll
    for (int rm = 0; rm < 2; ++rm)
#pragma unroll
      for (int rn = 0; rn < 2; ++rn) {
        if (rm_w == rm && rn_w == rn) {
#pragma unroll
          for (int mi = 0; mi < 4; ++mi)
#pragma unroll
            for (int ni = 0; ni < 4; ++ni)
#pragma unroll
              for (int r = 0; r < 4; ++r) {
                const int row = mi * 16 + quad * 4 + r;
                float v = acc[mi][ni][r];
                if (BIAS) v += bias[m0 + rm * 64 + row];
                tile[row * 128 + colb + ni * 16 + l16] = v;
              }
        }
        __syncthreads();
#pragma unroll
        for (int i = 0; i < 4; ++i) {
          const int row = wave * 8 + i * 2 + (lane >> 5);
          const int cf  = (lane & 31) * 4;
          *(f32x4*)&C[(long)(m0 + rm * 64 + row) * ldc + n0 + rn * 128 + cf] =
              *(f32x4*)&tile[row * 128 + cf];
        }
        __syncthreads();
      }
  } else {
    if (EXP) {                         // exp + per-row sum atomics, in-place
#pragma unroll
      for (int mi = 0; mi < 4; ++mi)
#pragma unroll
        for (int r = 0; r < 4; ++r) {
          const int row = arow + mi * 16 + quad * 4 + r;
          float rs = 0.f;
#pragma unroll
          for (int ni = 0; ni < 4; ++ni) {
            float v = __expf(acc[mi][ni][r]);
            acc[mi][ni][r] = v; rs += v;
          }
          rs += __shfl_xor(rs, 1); rs += __shfl_xor(rs, 2);
          rs += __shfl_xor(rs, 4); rs += __shfl_xor(rs, 8);
          if (l16 == 0) atomicAdd(&rowsum[m0 + row], rs);
        }
    }
    short* tile = (short*)smem;        // 128 x 128 bf16 per round
#pragma unroll
    for (int rn = 0; rn < 2; ++rn) {
      if (rn_w == rn) {
#pragma unroll
        for (int mi = 0; mi < 4; ++mi)
#pragma unroll
          for (int ni = 0; ni < 4; ++ni)
#pragma unroll
            for (int r = 0; r < 4; ++r) {
              const int row = arow + mi * 16 + quad * 4 + r;
              float v = acc[mi][ni][r];
              if (BIAS) v += bias[m0 + row];
              tile[row * 128 + colb + ni * 16 + l16] = f2bf(v);
            }
      }
      __syncthreads();
#pragma unroll
      for (int i = 0; i < 4; ++i) {
        const int row = wave * 16 + i * 4 + (lane >> 4);
        const int cs  = l16 * 8;
        *(int4*)&C[(long)(m0 + row) * ldc + n0 + rn * 128 + cs] =
            *(int4*)&tile[row * 128 + cs];
      }
      __syncthreads();
    }
  }
}

// R5: counted-vmcnt 3-buffer pipeline (T4, m218).  The old 2-phase loop's
// __syncthreads drained vmcnt(0) every K-step, serializing the just-issued
// prefetch.  Now: prefetch depth 2; per-iter `s_waitcnt vmcnt(3)` (each
// stage = 3 gl_lds16/thread, so count>=3 lets the newest stage float) +
// raw s_barrier.  stage(t+2) targets buf (t-1)%3 whose ds_reads finished
// before each wave's iter-(t-1) MFMA (lgkmcnt) -> safe after iter-t barrier.
// Last iter peeled with vmcnt(0).  LDS 3x24KB = 72KB -> 2 blocks/CU.
#define WIDE_K_LOOP(A_, lda_, B_, ldb_, kbeg_, kend_)                        \
  {                                                                          \
    const int lrow = t >> 2;           /* 0..127 */                          \
    const int lk8  = (t & 3) * 8;                                            \
    auto stage = [&](int buf, int k0) {                                      \
      gl_lds16(A_ + (long)(m0 + lrow) * lda_ + k0 + lk8,                     \
               smem + buf * 24576 + wave * 1024);                            \
      _Pragma("unroll")                                                      \
      for (int s = 0; s < 2; ++s)                                            \
        gl_lds16(B_ + (long)(n0 + s * 128 + lrow) * ldb_ + k0 + lk8,         \
                 smem + buf * 24576 + 8192 + s * 8192 + wave * 1024);        \
    };                                                                       \
    auto compute = [&](int buf) {                                            \
      const short* As = (const short*)(smem + buf * 24576);                  \
      const short* Bs = (const short*)(smem + buf * 24576 + 8192);           \
      bf16x8 af[4], bfr[4];                                                  \
      _Pragma("unroll")                                                      \
      for (int i = 0; i < 4; ++i)                                            \
        af[i] = *(const bf16x8*)&As[(arow + i * 16 + l16) * 32 + quad * 8];  \
      _Pragma("unroll")                                                      \
      for (int i = 0; i < 4; ++i)                                            \
        bfr[i] = *(const bf16x8*)&Bs[(brow + i * 16 + l16) * 32 + quad * 8]; \
      _Pragma("unroll")                                                      \
      for (int mi = 0; mi < 4; ++mi)                                         \
        _Pragma("unroll")                                                    \
        for (int ni = 0; ni < 4; ++ni)                                       \
          acc[mi][ni] = __builtin_amdgcn_mfma_f32_16x16x32_bf16(             \
              af[mi], bfr[ni], acc[mi][ni], 0, 0, 0);                        \
    };                                                                       \
    stage(0, kbeg_);                                                         \
    stage(1, kbeg_ + 32);                                                    \
    int cur = 0;                                                             \
    for (int k0 = kbeg_; k0 < kend_ - 32; k0 += 32) {                        \
      asm volatile("s_waitcnt vmcnt(3)" ::: "memory");                       \
      __builtin_amdgcn_s_barrier();                                          \
      __builtin_amdgcn_sched_barrier(0);                                     \
      if (k0 + 64 < kend_) {                                                 \
        int nb = cur + 2; if (nb >= 3) nb -= 3;                              \
        stage(nb, k0 + 64);                                                  \
      }                                                                      \
      compute(cur);                                                          \
      ++cur; if (cur == 3) cur = 0;                                          \
    }                                                                        \
    asm volatile("s_waitcnt vmcnt(0)" ::: "memory");                         \
    __builtin_amdgcn_s_barrier();                                            \
    __builtin_amdgcn_sched_barrier(0);                                       \
    compute(cur);                                                            \
    __syncthreads();                   /* protect epilogue smem reuse */     \
  }

template <typename OutT, bool BIAS, bool EXP>
__global__ __launch_bounds__(512, 4)
void gemm_nt_wide(const short* __restrict__ A, long sA, int lda,
                  const short* __restrict__ B, long sB, int ldb,
                  OutT* __restrict__ C, long sC, int ldc,
                  const float* __restrict__ bias, float* __restrict__ rowsum,
                  int K)
{
  int bx = blockIdx.x, by = blockIdx.y, bz = blockIdx.z;
  swz_blk(bx, by, bz);

  A += (long)bz * sA;
  B += (long)bz * sB;
  C += (long)bz * sC;
  if (EXP) rowsum += (long)bz * 512;

  __shared__ char smem[73728];         // 3x24KB staging; epilogue uses 32KB

  const int t    = threadIdx.x;
  const int wave = t >> 6, lane = t & 63;
  const int quad = lane >> 4, l16 = lane & 15;
  const int m0 = by * 128, n0 = bx * 256;
  const int arow = (wave >> 2) * 64, brow = (wave & 3) * 64;

  f32x4 acc[4][4];
#pragma unroll
  for (int i = 0; i < 4; ++i)
#pragma unroll
    for (int j = 0; j < 4; ++j) acc[i][j] = (f32x4){0.f, 0.f, 0.f, 0.f};

  WIDE_K_LOOP(A, lda, B, ldb, 0, K)

  epilogue_store_wide<OutT, BIAS, EXP>(acc, smem, C, ldc, m0, n0, bias,
                                       rowsum, t);
}

// split-K wide: M=512, N=512, K=4096 in 4 chunks of 1024, fp32 partials.
__global__ __launch_bounds__(512, 4)
void gemm_sk_wide(const short* __restrict__ Ab, const short* __restrict__ Bb,
                  float* __restrict__ Cp)
{
  int bx = blockIdx.x, by = blockIdx.y, bz = blockIdx.z;
  swz_blk(bx, by, bz);

  const int b = bz >> 2, s = bz & 3;
  const short* A = Ab + (long)b * 2097152;
  const short* B = Bb + (long)b * 2097152;
  float* C = Cp + (long)(s * 16 + b) * 262144;

  __shared__ char smem[73728];

  const int t    = threadIdx.x;
  const int wave = t >> 6, lane = t & 63;
  const int quad = lane >> 4, l16 = lane & 15;
  const int m0 = by * 128, n0 = bx * 256;
  const int arow = (wave >> 2) * 64, brow = (wave & 3) * 64;
  const int kbeg = s * 1024, kend = kbeg + 1024;

  f32x4 acc[4][4];
#pragma unroll
  for (int i = 0; i < 4; ++i)
#pragma unroll
    for (int j = 0; j < 4; ++j) acc[i][j] = (f32x4){0.f, 0.f, 0.f, 0.f};

  WIDE_K_LOOP(A, 4096, B, 4096, kbeg, kend)

  epilogue_store_wide<float, false, false>(acc, smem, C, 512, m0, n0, nullptr,
                                           nullptr, t);
}

// sum 4 fp32 split-K partials, normalize by 1/rowsum (softmax denom) -> bf16
__global__ void reduce_sk(const float* __restrict__ p, short* __restrict__ o,
                          const float* __restrict__ s) {
  const long i = ((long)blockIdx.x * 256 + threadIdx.x) * 4;
  const float inv = 1.f / s[i >> 9];     // i/512 = b*512 + d
  f32x4 a = *(const f32x4*)&p[i];
  f32x4 b = *(const f32x4*)&p[i + 4194304];
  f32x4 c = *(const f32x4*)&p[i + 2 * 4194304];
  f32x4 d = *(const f32x4*)&p[i + 3 * 4194304];
  short r[4];
#pragma unroll
  for (int j = 0; j < 4; ++j) r[j] = f2bf((a[j] + b[j] + c[j] + d[j]) * inv);
  *(long*)&o[i] = *(long*)r;
}

// xT[b][l][c] = bf16(x[b][c][l]);  xb[b][c][l] = bf16(x[b][c][l])
// R5: batch the 4 global loads into regs BEFORE any consumer (R4 showed
// VGPR=24 -> compiler serialized loads, 2.5 TB/s latency-bound), and batch
// the 16 LDS column reads before the xT stores.
__global__ void transpose_cast(const float* __restrict__ x,
                               short* __restrict__ xT, short* __restrict__ xb)
{
  __shared__ short tile[64][73];
  x  += (long)blockIdx.z * 2097152;
  xT += (long)blockIdx.z * 2097152;
  xb += (long)blockIdx.z * 2097152;
  const int l0 = blockIdx.x * 64, c0 = blockIdx.y * 64;
  const int t  = threadIdx.x;
  const int rr = t >> 4;            // 0..15
  const int q4 = (t & 15) * 4;      // 0..60

  f32x4 v[4];
#pragma unroll
  for (int i = 0; i < 4; ++i)
    v[i] = *(const f32x4*)&x[(long)(c0 + rr + i * 16) * 4096 + l0 + q4];

  short s4[4][4];
#pragma unroll
  for (int i = 0; i < 4; ++i) {
#pragma unroll
    for (int j = 0; j < 4; ++j) s4[i][j] = f2bf(v[i][j]);
    *(long*)&xb[(long)(c0 + rr + i * 16) * 4096 + l0 + q4] = *(long*)s4[i];
#pragma unroll
    for (int j = 0; j < 4; ++j) tile[rr + i * 16][q4 + j] = s4[i][j];
  }
  __syncthreads();

  short o4[4][4];
#pragma unroll
  for (int i = 0; i < 4; ++i)
#pragma unroll
    for (int j = 0; j < 4; ++j) o4[i][j] = tile[q4 + j][rr + i * 16];
#pragma unroll
  for (int i = 0; i < 4; ++i)
    *(long*)&xT[(long)(l0 + rr + i * 16) * 512 + c0 + q4] = *(long*)o4[i];
}

DEVINL float to_f(float v) { return v; }
DEVINL float to_f(short v) { return bf2f(v); }

template <typename InT, typename OutT>
__global__ void transpose_k(const InT* __restrict__ src, OutT* __restrict__ dst,
                            int R, int Cc, long ss, long ds)
{
  __shared__ float tile[32][33];
  src += (long)blockIdx.z * ss;
  dst += (long)blockIdx.z * ds;
  const int c0 = blockIdx.x * 32, r0 = blockIdx.y * 32;
  const int tx = threadIdx.x, ty = threadIdx.y;
#pragma unroll
  for (int i = 0; i < 4; ++i)
    tile[ty + i * 8][tx] = to_f(src[(long)(r0 + ty + i * 8) * Cc + c0 + tx]);
  __syncthreads();
#pragma unroll
  for (int i = 0; i < 4; ++i) {
    float v = tile[tx][ty + i * 8];
    if constexpr (std::is_same<OutT, float>::value)
      dst[(long)(c0 + ty + i * 8) * R + r0 + tx] = v;
    else
      dst[(long)(c0 + ty + i * 8) * R + r0 + tx] = f2bf(v);
  }
}

// cast both weight mats to bf16; blocks 0-31 additionally zero ssum[8192]
__global__ void cast_weights(const float* __restrict__ wq, short* __restrict__ wqb,
                             const float* __restrict__ wo, short* __restrict__ wob,
                             float* __restrict__ ssum) {
  const int i = blockIdx.x * 256 + threadIdx.x;
  if (blockIdx.x < 32) ssum[i] = 0.f;
  if (i < 786432) wqb[i] = f2bf(wq[i]);
  else            wob[i - 786432] = f2bf(wo[i - 786432]);
}

extern "C" void kernel_launch(void* const* d_in, const int* in_sizes, int n_in,
                              void* d_out, int out_size, void* d_ws, size_t ws_size,
                              hipStream_t stream) {
  // B=16, C=512, L=4096
  const float* x     = (const float*)d_in[0];
  const float* w_qkv = (const float*)d_in[1];
  const float* w_out = (const float*)d_in[2];
  const float* b_out = (const float*)d_in[3];
  float* out = (float*)d_out;

  const long CL = (long)512 * 4096;   // 2,097,152 per-batch elems
  const long CC = (long)512 * 512;

  char* ws = (char*)d_ws;
  short* xT  = (short*)(ws);                 //  67,108,864 B  [b][l][c]
  short* xb  = (short*)(ws + 67108864);      //  67,108,864 B  [b][c][l]
  short* kbf = (short*)(ws + 134217728);     //  67,108,864 B  [b][d][l]  exp(k)
  float* Pp  = (float*)(ws + 201326592);     //  67,108,864 B  [s][b][d][c] fp32
  short* P   = (short*)(ws + 268435456);     //   8,388,608 B  [b][d][c]
  short* U   = (short*)(ws + 276824064);     //     524,288 B  U = w_o·w_v [o][c]
  short* wvT = (short*)(ws + 277348352);     //     524,288 B  w_v^T [c][e]
  short* M2  = (short*)(ws + 285212672);     //   8,388,608 B  [b][o][d]
  short* M3  = (short*)(ws + 293601280);     //   8,388,608 B  [b][o][c]
  short* wqb = (short*)(ws + 301989888);     //   1,572,864 B
  short* wob = (short*)(ws + 303562752);     //     524,288 B
  short* wqT = (short*)(ws + 304087040);     //     524,288 B  w_q^T [c][d]
  // ssum[b][d] (32 KB) aliases M3's region: M3 is first written AFTER
  // reduce_sk has consumed ssum (stream-ordered), so no conflict.
  float* ssum = (float*)(ws + 293601280);

  cast_weights<<<4096, 256, 0, stream>>>(w_qkv, wqb, w_out, wob, ssum);

  // wqT[c][d] = bf16(w_q[d][c]);  wvT[c][e] = bf16(w_v[e][c])
  transpose_k<float, short><<<dim3(16, 16, 1), dim3(32, 8), 0, stream>>>(
      w_qkv, wqT, 512, 512, 0, 0);
  transpose_k<short, short><<<dim3(16, 16, 1), dim3(32, 8), 0, stream>>>(
      wqb + 2 * CC, wvT, 512, 512, 0, 0);

  // U[o][c] = sum_e w_o[o][e]·w_v[e][c]  (batch-independent fold:
  // M2 = w_o·ctx^T = (w_o·w_v)·P^T = U·P^T)
  gemm_nt<short, false, false><<<dim3(4, 4, 1), 256, 0, stream>>>(
      wob, 0, 512, wvT, 0, 512, U, 0, 512, nullptr, nullptr, 512);

  // xT + xb in one pass over x
  transpose_cast<<<dim3(64, 8, 16), 256, 0, stream>>>(x, xT, xb);

  // kbf[b][d][l] = exp(sum_c w_k[d][c]·xT[b][l][c]); ssum[b][d] = sum_l exp
  gemm_nt_wide<short, false, true><<<dim3(16, 4, 16), 512, 0, stream>>>(
      wqb + CC, 0, 512, xT, CL, 512, kbf, CL, 4096, nullptr, ssum, 512);

  // P[b][d][c] = (1/ssum[b][d]) * sum_l exp(k)[d][l]·xb[c][l]
  gemm_sk_wide<<<dim3(2, 4, 64), 512, 0, stream>>>(kbf, xb, Pp);
  reduce_sk<<<4096, 256, 0, stream>>>(Pp, P, ssum);

  // M2[b][o][d] = sum_c U[o][c]·P[b][d][c]   (M=N=512, K=512)
  gemm_nt<short, false, false><<<dim3(4, 4, 16), 256, 0, stream>>>(
      U, 0, 512, P, CC, 512, M2, CC, 512, nullptr, nullptr, 512);

  // M3[b][o][c] = sum_d M2[o][d]·wqT[c][d]   (M=N=512, K=512)
  gemm_nt<short, false, false><<<dim3(4, 4, 16), 256, 0, stream>>>(
      M2, CC, 512, wqT, 0, 512, M3, CC, 512, nullptr, nullptr, 512);

  // out[b][o][l] = sum_c M3[o][c]·xT[b][l][c] + b_out[o]  (fp32)
  gemm_nt_wide<float, true, false><<<dim3(16, 4, 16), 512, 0, stream>>>(
      M3, CC, 512, xT, CL, 512, out, CL, 4096, b_out, nullptr, 512);
}

// Round 6
// 469.589 us; speedup vs baseline: 1.1431x; 1.0271x over previous
//
#include <hip/hip_runtime.h>
#include <hip/hip_bf16.h>
#include <type_traits>

#define DEVINL __device__ __forceinline__

typedef float f32x4 __attribute__((ext_vector_type(4)));
typedef __bf16 bf16x8 __attribute__((ext_vector_type(8)));

DEVINL float bf2f(short s) {
  unsigned u = ((unsigned)(unsigned short)s) << 16;
  float f; __builtin_memcpy(&f, &u, 4); return f;
}
DEVINL short f2bf(float f) {
  unsigned u; __builtin_memcpy(&u, &f, 4);
  u += 0x7fff + ((u >> 16) & 1);          // round-nearest-even
  return (short)(u >> 16);
}

DEVINL void gl_lds16(const void* g, void* l) {
  __builtin_amdgcn_global_load_lds(
      (const __attribute__((address_space(1))) void*)g,
      (__attribute__((address_space(3))) void*)l, 16, 0, 0);
}

// XCD-aware block swizzle (T1, m192).  R2: gemm_sk FETCH 276 MB -> 68 MB.
// Requires nwg % 8 == 0 (grids: 1024/512/256/16).
DEVINL void swz_blk(int& bx, int& by, int& bz) {
  const int gx = gridDim.x, gy = gridDim.y;
  const int tpz = gx * gy;
  const int nwg = tpz * gridDim.z;
  int fid = bx + gx * (by + gy * bz);
  fid = (fid & 7) * (nwg >> 3) + (fid >> 3);
  bz = fid / tpz;
  const int r = fid - bz * tpz;
  by = r % gy;            // m fastest: consecutive blocks share the B n-panel
  bx = r / gy;
}

// ---------- 128x128 tile / 256-thread path (small GEMMs) ----------

template <typename OutT, bool BIAS, bool EXP>
DEVINL void epilogue_store(f32x4 (&acc)[4][4], char* smem,
                           OutT* __restrict__ C, int ldc, int m0, int n0,
                           const float* __restrict__ bias,
                           float* __restrict__ rowsum, int t) {
  const int wave = t >> 6, lane = t & 63;
  const int quad = lane >> 4, l16 = lane & 15;
  const int arow = (wave >> 1) * 64, brow = (wave & 1) * 64;
  if constexpr (std::is_same<OutT, float>::value) {
    float* tile = (float*)smem;          // 64 x 128 fp32 per round
#pragma unroll
    for (int rnd = 0; rnd < 2; ++rnd) {
      if ((arow >> 6) == rnd) {
#pragma unroll
        for (int mi = 0; mi < 4; ++mi)
#pragma unroll
          for (int ni = 0; ni < 4; ++ni) {
            const int col = brow + ni * 16 + l16;
#pragma unroll
            for (int r = 0; r < 4; ++r) {
              const int row = mi * 16 + quad * 4 + r;
              float v = acc[mi][ni][r];
              if (BIAS) v += bias[m0 + rnd * 64 + row];
              tile[row * 128 + col] = v;
            }
          }
      }
      __syncthreads();
#pragma unroll
      for (int i = 0; i < 8; ++i) {
        const int row = wave * 16 + i * 2 + (lane >> 5);
        const int cf  = (lane & 31) * 4;
        f32x4 v = *(f32x4*)&tile[row * 128 + cf];
        *(f32x4*)&C[(long)(m0 + rnd * 64 + row) * ldc + n0 + cf] = v;
      }
      __syncthreads();
    }
  } else {
    short* tile = (short*)smem;          // 128 x 128 bf16
#pragma unroll
    for (int mi = 0; mi < 4; ++mi)
#pragma unroll
      for (int r = 0; r < 4; ++r) {
        const int row = arow + mi * 16 + quad * 4 + r;
        float rs = 0.f;
#pragma unroll
        for (int ni = 0; ni < 4; ++ni) {
          const int col = brow + ni * 16 + l16;
          float v = acc[mi][ni][r];
          if (BIAS) v += bias[m0 + row];
          if (EXP) { v = __expf(v); rs += v; }
          tile[row * 128 + col] = f2bf(v);
        }
        if (EXP) {
          rs += __shfl_xor(rs, 1); rs += __shfl_xor(rs, 2);
          rs += __shfl_xor(rs, 4); rs += __shfl_xor(rs, 8);
          if (l16 == 0) atomicAdd(&rowsum[m0 + row], rs);
        }
      }
    __syncthreads();
#pragma unroll
    for (int i = 0; i < 8; ++i) {
      const int row = wave * 32 + i * 4 + (lane >> 4);
      const int cs  = l16 * 8;
      int4 v = *(int4*)&tile[row * 128 + cs];
      *(int4*)&C[(long)(m0 + row) * ldc + n0 + cs] = v;
    }
  }
}

// 2-phase double-buffered K loop (small GEMMs, unchanged).
#define GEMM_K_LOOP(A_, lda_, B_, ldb_, kbeg_, kend_)                        \
  {                                                                          \
    const int lrow = t >> 2;                                                 \
    const int lk8  = (t & 3) * 8;                                            \
    auto stage = [&](int buf, int k0) {                                      \
      _Pragma("unroll")                                                      \
      for (int s = 0; s < 2; ++s) {                                          \
        gl_lds16(A_ + (long)(m0 + s * 64 + lrow) * lda_ + k0 + lk8,          \
                 smem + buf * 16384 + s * 4096 + wave * 1024);               \
        gl_lds16(B_ + (long)(n0 + s * 64 + lrow) * ldb_ + k0 + lk8,          \
                 smem + buf * 16384 + 8192 + s * 4096 + wave * 1024);        \
      }                                                                      \
    };                                                                       \
    stage(0, kbeg_);                                                         \
    __syncthreads();                                                         \
    int cur = 0;                                                             \
    for (int k0 = kbeg_; k0 < kend_; k0 += 32) {                             \
      if (k0 + 32 < kend_) stage(cur ^ 1, k0 + 32);                          \
      const short* As = (const short*)(smem + cur * 16384);                  \
      const short* Bs = (const short*)(smem + cur * 16384 + 8192);           \
      bf16x8 af[4], bfr[4];                                                  \
      _Pragma("unroll")                                                      \
      for (int i = 0; i < 4; ++i)                                            \
        af[i] = *(const bf16x8*)&As[(arow + i * 16 + l16) * 32 + quad * 8];  \
      _Pragma("unroll")                                                      \
      for (int i = 0; i < 4; ++i)                                            \
        bfr[i] = *(const bf16x8*)&Bs[(brow + i * 16 + l16) * 32 + quad * 8]; \
      _Pragma("unroll")                                                      \
      for (int mi = 0; mi < 4; ++mi)                                         \
        _Pragma("unroll")                                                    \
        for (int ni = 0; ni < 4; ++ni)                                       \
          acc[mi][ni] = __builtin_amdgcn_mfma_f32_16x16x32_bf16(             \
              af[mi], bfr[ni], acc[mi][ni], 0, 0, 0);                        \
      __syncthreads();                                                       \
      cur ^= 1;                                                              \
    }                                                                        \
  }

template <typename OutT, bool BIAS, bool EXP>
__global__ __launch_bounds__(256, 4)
void gemm_nt(const short* __restrict__ A, long sA, int lda,
             const short* __restrict__ B, long sB, int ldb,
             OutT* __restrict__ C, long sC, int ldc,
             const float* __restrict__ bias, float* __restrict__ rowsum, int K)
{
  int bx = blockIdx.x, by = blockIdx.y, bz = blockIdx.z;
  swz_blk(bx, by, bz);

  A += (long)bz * sA;
  B += (long)bz * sB;
  C += (long)bz * sC;
  if (EXP) rowsum += (long)bz * 512;

  __shared__ char smem[32768];

  const int t    = threadIdx.x;
  const int wave = t >> 6, lane = t & 63;
  const int quad = lane >> 4, l16 = lane & 15;
  const int m0 = by * 128, n0 = bx * 128;
  const int arow = (wave >> 1) * 64, brow = (wave & 1) * 64;

  f32x4 acc[4][4];
#pragma unroll
  for (int i = 0; i < 4; ++i)
#pragma unroll
    for (int j = 0; j < 4; ++j) acc[i][j] = (f32x4){0.f, 0.f, 0.f, 0.f};

  GEMM_K_LOOP(A, lda, B, ldb, 0, K)

  epilogue_store<OutT, BIAS, EXP>(acc, smem, C, ldc, m0, n0, bias, rowsum, t);
}

// ---------- 128x256 tile / 512-thread / 8-wave path (big GEMMs) ----------

template <typename OutT, bool BIAS, bool EXP>
DEVINL void epilogue_store_wide(f32x4 (&acc)[4][4], char* smem,
                                OutT* __restrict__ C, int ldc, int m0, int n0,
                                const float* __restrict__ bias,
                                float* __restrict__ rowsum, int t) {
  const int wave = t >> 6, lane = t & 63;
  const int quad = lane >> 4, l16 = lane & 15;
  const int arow = (wave >> 2) * 64, brow = (wave & 3) * 64;
  const int rn_w = brow >> 7;          // this wave's n-round
  const int colb = brow & 64;          // col base within the 128-wide round
  if constexpr (std::is_same<OutT, float>::value) {
    float* tile = (float*)smem;        // 64 x 128 fp32 per round
    const int rm_w = arow >> 6;
#pragma unroll
    for (int rm = 0; rm < 2; ++rm)
#pragma unroll
      for (int rn = 0; rn < 2; ++rn) {
        if (rm_w == rm && rn_w == rn) {
#pragma unroll
          for (int mi = 0; mi < 4; ++mi)
#pragma unroll
            for (int ni = 0; ni < 4; ++ni)
#pragma unroll
              for (int r = 0; r < 4; ++r) {
                const int row = mi * 16 + quad * 4 + r;
                float v = acc[mi][ni][r];
                if (BIAS) v += bias[m0 + rm * 64 + row];
                tile[row * 128 + colb + ni * 16 + l16] = v;
              }
        }
        __syncthreads();
#pragma unroll
        for (int i = 0; i < 4; ++i) {
          const int row = wave * 8 + i * 2 + (lane >> 5);
          const int cf  = (lane & 31) * 4;
          *(f32x4*)&C[(long)(m0 + rm * 64 + row) * ldc + n0 + rn * 128 + cf] =
              *(f32x4*)&tile[row * 128 + cf];
        }
        __syncthreads();
      }
  } else {
    if (EXP) {                         // exp + per-row sum atomics, in-place
#pragma unroll
      for (int mi = 0; mi < 4; ++mi)
#pragma unroll
        for (int r = 0; r < 4; ++r) {
          const int row = arow + mi * 16 + quad * 4 + r;
          float rs = 0.f;
#pragma unroll
          for (int ni = 0; ni < 4; ++ni) {
            float v = __expf(acc[mi][ni][r]);
            acc[mi][ni][r] = v; rs += v;
          }
          rs += __shfl_xor(rs, 1); rs += __shfl_xor(rs, 2);
          rs += __shfl_xor(rs, 4); rs += __shfl_xor(rs, 8);
          if (l16 == 0) atomicAdd(&rowsum[m0 + row], rs);
        }
    }
    short* tile = (short*)smem;        // 128 x 128 bf16 per round
#pragma unroll
    for (int rn = 0; rn < 2; ++rn) {
      if (rn_w == rn) {
#pragma unroll
        for (int mi = 0; mi < 4; ++mi)
#pragma unroll
          for (int ni = 0; ni < 4; ++ni)
#pragma unroll
            for (int r = 0; r < 4; ++r) {
              const int row = arow + mi * 16 + quad * 4 + r;
              float v = acc[mi][ni][r];
              if (BIAS) v += bias[m0 + row];
              tile[row * 128 + colb + ni * 16 + l16] = f2bf(v);
            }
      }
      __syncthreads();
#pragma unroll
      for (int i = 0; i < 4; ++i) {
        const int row = wave * 16 + i * 4 + (lane >> 4);
        const int cs  = l16 * 8;
        *(int4*)&C[(long)(m0 + row) * ldc + n0 + rn * 128 + cs] =
            *(int4*)&tile[row * 128 + cs];
      }
      __syncthreads();
    }
  }
}

// counted-vmcnt 3-buffer pipeline (T4, m218).  Prefetch depth 2; per-iter
// `s_waitcnt vmcnt(3)` + raw s_barrier; last iter peeled with vmcnt(0).
#define WIDE_K_LOOP(A_, lda_, B_, ldb_, kbeg_, kend_)                        \
  {                                                                          \
    const int lrow = t >> 2;           /* 0..127 */                          \
    const int lk8  = (t & 3) * 8;                                            \
    auto stage = [&](int buf, int k0) {                                      \
      gl_lds16(A_ + (long)(m0 + lrow) * lda_ + k0 + lk8,                     \
               smem + buf * 24576 + wave * 1024);                            \
      _Pragma("unroll")                                                      \
      for (int s = 0; s < 2; ++s)                                            \
        gl_lds16(B_ + (long)(n0 + s * 128 + lrow) * ldb_ + k0 + lk8,         \
                 smem + buf * 24576 + 8192 + s * 8192 + wave * 1024);        \
    };                                                                       \
    auto compute = [&](int buf) {                                            \
      const short* As = (const short*)(smem + buf * 24576);                  \
      const short* Bs = (const short*)(smem + buf * 24576 + 8192);           \
      bf16x8 af[4], bfr[4];                                                  \
      _Pragma("unroll")                                                      \
      for (int i = 0; i < 4; ++i)                                            \
        af[i] = *(const bf16x8*)&As[(arow + i * 16 + l16) * 32 + quad * 8];  \
      _Pragma("unroll")                                                      \
      for (int i = 0; i < 4; ++i)                                            \
        bfr[i] = *(const bf16x8*)&Bs[(brow + i * 16 + l16) * 32 + quad * 8]; \
      _Pragma("unroll")                                                      \
      for (int mi = 0; mi < 4; ++mi)                                         \
        _Pragma("unroll")                                                    \
        for (int ni = 0; ni < 4; ++ni)                                       \
          acc[mi][ni] = __builtin_amdgcn_mfma_f32_16x16x32_bf16(             \
              af[mi], bfr[ni], acc[mi][ni], 0, 0, 0);                        \
    };                                                                       \
    stage(0, kbeg_);                                                         \
    stage(1, kbeg_ + 32);                                                    \
    int cur = 0;                                                             \
    for (int k0 = kbeg_; k0 < kend_ - 32; k0 += 32) {                        \
      asm volatile("s_waitcnt vmcnt(3)" ::: "memory");                       \
      __builtin_amdgcn_s_barrier();                                          \
      __builtin_amdgcn_sched_barrier(0);                                     \
      if (k0 + 64 < kend_) {                                                 \
        int nb = cur + 2; if (nb >= 3) nb -= 3;                              \
        stage(nb, k0 + 64);                                                  \
      }                                                                      \
      compute(cur);                                                          \
      ++cur; if (cur == 3) cur = 0;                                          \
    }                                                                        \
    asm volatile("s_waitcnt vmcnt(0)" ::: "memory");                         \
    __builtin_amdgcn_s_barrier();                                            \
    __builtin_amdgcn_sched_barrier(0);                                       \
    compute(cur);                                                            \
    __syncthreads();                   /* protect epilogue smem reuse */     \
  }

template <typename OutT, bool BIAS, bool EXP>
__global__ __launch_bounds__(512, 4)
void gemm_nt_wide(const short* __restrict__ A, long sA, int lda,
                  const short* __restrict__ B, long sB, int ldb,
                  OutT* __restrict__ C, long sC, int ldc,
                  const float* __restrict__ bias, float* __restrict__ rowsum,
                  int K)
{
  int bx = blockIdx.x, by = blockIdx.y, bz = blockIdx.z;
  swz_blk(bx, by, bz);

  A += (long)bz * sA;
  B += (long)bz * sB;
  C += (long)bz * sC;
  if (EXP) rowsum += (long)bz * 512;

  __shared__ char smem[73728];         // 3x24KB staging; epilogue uses 32KB

  const int t    = threadIdx.x;
  const int wave = t >> 6, lane = t & 63;
  const int quad = lane >> 4, l16 = lane & 15;
  const int m0 = by * 128, n0 = bx * 256;
  const int arow = (wave >> 2) * 64, brow = (wave & 3) * 64;

  f32x4 acc[4][4];
#pragma unroll
  for (int i = 0; i < 4; ++i)
#pragma unroll
    for (int j = 0; j < 4; ++j) acc[i][j] = (f32x4){0.f, 0.f, 0.f, 0.f};

  WIDE_K_LOOP(A, lda, B, ldb, 0, K)

  epilogue_store_wide<OutT, BIAS, EXP>(acc, smem, C, ldc, m0, n0, bias,
                                       rowsum, t);
}

// split-K wide: M=512, N=512, K=4096 in 2 chunks of 2048, fp32 partials.
// R6: split 4->2 — halves partial traffic, doubles K-steps/block (64) for
// prologue amortization.  z = b*2 + s, grid (2,4,32) = 256 blocks.
__global__ __launch_bounds__(512, 4)
void gemm_sk_wide(const short* __restrict__ Ab, const short* __restrict__ Bb,
                  float* __restrict__ Cp)
{
  int bx = blockIdx.x, by = blockIdx.y, bz = blockIdx.z;
  swz_blk(bx, by, bz);

  const int b = bz >> 1, s = bz & 1;
  const short* A = Ab + (long)b * 2097152;
  const short* B = Bb + (long)b * 2097152;
  float* C = Cp + (long)(s * 16 + b) * 262144;

  __shared__ char smem[73728];

  const int t    = threadIdx.x;
  const int wave = t >> 6, lane = t & 63;
  const int quad = lane >> 4, l16 = lane & 15;
  const int m0 = by * 128, n0 = bx * 256;
  const int arow = (wave >> 2) * 64, brow = (wave & 3) * 64;
  const int kbeg = s * 2048, kend = kbeg + 2048;

  f32x4 acc[4][4];
#pragma unroll
  for (int i = 0; i < 4; ++i)
#pragma unroll
    for (int j = 0; j < 4; ++j) acc[i][j] = (f32x4){0.f, 0.f, 0.f, 0.f};

  WIDE_K_LOOP(A, 4096, B, 4096, kbeg, kend)

  epilogue_store_wide<float, false, false>(acc, smem, C, 512, m0, n0, nullptr,
                                           nullptr, t);
}

// sum 2 fp32 split-K partials, normalize by 1/rowsum (softmax denom) -> bf16
__global__ void reduce_sk(const float* __restrict__ p, short* __restrict__ o,
                          const float* __restrict__ s) {
  const long i = ((long)blockIdx.x * 256 + threadIdx.x) * 4;
  const float inv = 1.f / s[i >> 9];     // i/512 = b*512 + d
  f32x4 a = *(const f32x4*)&p[i];
  f32x4 b = *(const f32x4*)&p[i + 4194304];
  short r[4];
#pragma unroll
  for (int j = 0; j < 4; ++j) r[j] = f2bf((a[j] + b[j]) * inv);
  *(long*)&o[i] = *(long*)r;
}

// xT[b][l][c] = bf16(x[b][c][l]);  xb[b][c][l] = bf16(x[b][c][l])
// R6: hard sched_barrier(0) fences — R5's reg arrays were re-serialized by
// the scheduler (VGPR stayed 24, 2.5 TB/s latency-bound).  The fence forces
// all 4 global loads in flight before any consumer.
__global__ void transpose_cast(const float* __restrict__ x,
                               short* __restrict__ xT, short* __restrict__ xb)
{
  __shared__ short tile[64][73];
  x  += (long)blockIdx.z * 2097152;
  xT += (long)blockIdx.z * 2097152;
  xb += (long)blockIdx.z * 2097152;
  const int l0 = blockIdx.x * 64, c0 = blockIdx.y * 64;
  const int t  = threadIdx.x;
  const int rr = t >> 4;            // 0..15
  const int q4 = (t & 15) * 4;      // 0..60

  f32x4 v[4];
#pragma unroll
  for (int i = 0; i < 4; ++i)
    v[i] = *(const f32x4*)&x[(long)(c0 + rr + i * 16) * 4096 + l0 + q4];
  __builtin_amdgcn_sched_barrier(0);   // all 4 loads issued before any use

  short s4[4][4];
#pragma unroll
  for (int i = 0; i < 4; ++i) {
#pragma unroll
    for (int j = 0; j < 4; ++j) s4[i][j] = f2bf(v[i][j]);
    *(long*)&xb[(long)(c0 + rr + i * 16) * 4096 + l0 + q4] = *(long*)s4[i];
#pragma unroll
    for (int j = 0; j < 4; ++j) tile[rr + i * 16][q4 + j] = s4[i][j];
  }
  __syncthreads();

  short o4[4][4];
#pragma unroll
  for (int i = 0; i < 4; ++i)
#pragma unroll
    for (int j = 0; j < 4; ++j) o4[i][j] = tile[q4 + j][rr + i * 16];
  __builtin_amdgcn_sched_barrier(0);   // batch LDS reads before stores
#pragma unroll
  for (int i = 0; i < 4; ++i)
    *(long*)&xT[(long)(l0 + rr + i * 16) * 512 + c0 + q4] = *(long*)o4[i];
}

DEVINL float to_f(float v) { return v; }
DEVINL float to_f(short v) { return bf2f(v); }

template <typename InT, typename OutT>
__global__ void transpose_k(const InT* __restrict__ src, OutT* __restrict__ dst,
                            int R, int Cc, long ss, long ds)
{
  __shared__ float tile[32][33];
  src += (long)blockIdx.z * ss;
  dst += (long)blockIdx.z * ds;
  const int c0 = blockIdx.x * 32, r0 = blockIdx.y * 32;
  const int tx = threadIdx.x, ty = threadIdx.y;
#pragma unroll
  for (int i = 0; i < 4; ++i)
    tile[ty + i * 8][tx] = to_f(src[(long)(r0 + ty + i * 8) * Cc + c0 + tx]);
  __syncthreads();
#pragma unroll
  for (int i = 0; i < 4; ++i) {
    float v = tile[tx][ty + i * 8];
    if constexpr (std::is_same<OutT, float>::value)
      dst[(long)(c0 + ty + i * 8) * R + r0 + tx] = v;
    else
      dst[(long)(c0 + ty + i * 8) * R + r0 + tx] = f2bf(v);
  }
}

// cast both weight mats to bf16; blocks 0-31 additionally zero ssum[8192]
__global__ void cast_weights(const float* __restrict__ wq, short* __restrict__ wqb,
                             const float* __restrict__ wo, short* __restrict__ wob,
                             float* __restrict__ ssum) {
  const int i = blockIdx.x * 256 + threadIdx.x;
  if (blockIdx.x < 32) ssum[i] = 0.f;
  if (i < 786432) wqb[i] = f2bf(wq[i]);
  else            wob[i - 786432] = f2bf(wo[i - 786432]);
}

extern "C" void kernel_launch(void* const* d_in, const int* in_sizes, int n_in,
                              void* d_out, int out_size, void* d_ws, size_t ws_size,
                              hipStream_t stream) {
  // B=16, C=512, L=4096
  const float* x     = (const float*)d_in[0];
  const float* w_qkv = (const float*)d_in[1];
  const float* w_out = (const float*)d_in[2];
  const float* b_out = (const float*)d_in[3];
  float* out = (float*)d_out;

  const long CL = (long)512 * 4096;   // 2,097,152 per-batch elems
  const long CC = (long)512 * 512;

  char* ws = (char*)d_ws;
  short* xT  = (short*)(ws);                 //  67,108,864 B  [b][l][c]
  short* xb  = (short*)(ws + 67108864);      //  67,108,864 B  [b][c][l]
  short* kbf = (short*)(ws + 134217728);     //  67,108,864 B  [b][d][l]  exp(k)
  float* Pp  = (float*)(ws + 201326592);     //  33,554,432 B  [s][b][d][c] fp32
  short* P   = (short*)(ws + 268435456);     //   8,388,608 B  [b][d][c]
  short* U   = (short*)(ws + 276824064);     //     524,288 B  U = w_o·w_v [o][c]
  short* wvT = (short*)(ws + 277348352);     //     524,288 B  w_v^T [c][e]
  short* M2  = (short*)(ws + 285212672);     //   8,388,608 B  [b][o][d]
  short* M3  = (short*)(ws + 293601280);     //   8,388,608 B  [b][o][c]
  short* wqb = (short*)(ws + 301989888);     //   1,572,864 B
  short* wob = (short*)(ws + 303562752);     //     524,288 B
  short* wqT = (short*)(ws + 304087040);     //     524,288 B  w_q^T [c][d]
  // ssum[b][d] (32 KB) aliases M3's region: M3 is first written AFTER
  // reduce_sk has consumed ssum (stream-ordered), so no conflict.
  float* ssum = (float*)(ws + 293601280);

  cast_weights<<<4096, 256, 0, stream>>>(w_qkv, wqb, w_out, wob, ssum);

  // wqT[c][d] = bf16(w_q[d][c]);  wvT[c][e] = bf16(w_v[e][c])
  transpose_k<float, short><<<dim3(16, 16, 1), dim3(32, 8), 0, stream>>>(
      w_qkv, wqT, 512, 512, 0, 0);
  transpose_k<short, short><<<dim3(16, 16, 1), dim3(32, 8), 0, stream>>>(
      wqb + 2 * CC, wvT, 512, 512, 0, 0);

  // U[o][c] = sum_e w_o[o][e]·w_v[e][c]  (batch-independent fold:
  // M2 = w_o·ctx^T = (w_o·w_v)·P^T = U·P^T)
  gemm_nt<short, false, false><<<dim3(4, 4, 1), 256, 0, stream>>>(
      wob, 0, 512, wvT, 0, 512, U, 0, 512, nullptr, nullptr, 512);

  // xT + xb in one pass over x
  transpose_cast<<<dim3(64, 8, 16), 256, 0, stream>>>(x, xT, xb);

  // kbf[b][d][l] = exp(sum_c w_k[d][c]·xT[b][l][c]); ssum[b][d] = sum_l exp
  gemm_nt_wide<short, false, true><<<dim3(16, 4, 16), 512, 0, stream>>>(
      wqb + CC, 0, 512, xT, CL, 512, kbf, CL, 4096, nullptr, ssum, 512);

  // P[b][d][c] = (1/ssum[b][d]) * sum_l exp(k)[d][l]·xb[c][l]  (split-K 2)
  gemm_sk_wide<<<dim3(2, 4, 32), 512, 0, stream>>>(kbf, xb, Pp);
  reduce_sk<<<4096, 256, 0, stream>>>(Pp, P, ssum);

  // M2[b][o][d] = sum_c U[o][c]·P[b][d][c]   (M=N=512, K=512)
  gemm_nt<short, false, false><<<dim3(4, 4, 16), 256, 0, stream>>>(
      U, 0, 512, P, CC, 512, M2, CC, 512, nullptr, nullptr, 512);

  // M3[b][o][c] = sum_d M2[o][d]·wqT[c][d]   (M=N=512, K=512)
  gemm_nt<short, false, false><<<dim3(4, 4, 16), 256, 0, stream>>>(
      M2, CC, 512, wqT, 0, 512, M3, CC, 512, nullptr, nullptr, 512);

  // out[b][o][l] = sum_c M3[o][c]·xT[b][l][c] + b_out[o]  (fp32)
  gemm_nt_wide<float, true, false><<<dim3(16, 4, 16), 512, 0, stream>>>(
      M3, CC, 512, xT, CL, 512, out, CL, 4096, b_out, nullptr, 512);
}